// Round 1
// baseline (3265.607 us; speedup 1.0000x reference)
//
#include <hip/hip_runtime.h>
#include <math.h>

// Problem constants
// B=8192, C=4, D=256, E=8, H=256, O=128, AQ=18, HQ=512, N=B*C=32768
// result buffer: (32768, 128) fp32 == (8192, 512) view. ws usage ~16.9 MB.

// ---------------- fused MoE kernel ----------------
// 64 tokens/block, 256 threads (mi=tid>>5 in [0,8), ci=tid&31).
// LDS (floats): xT[256][68] @0 (17408) | hT[256][68] @17408 (alias rT[128][68])
//               WS[16][256] @34816 (4096) | gld[64][8] @38912 (512)
// total 39424 floats = 157696 B dynamic LDS (<= 160 KiB)

#define XT_STRIDE 68

__device__ __forceinline__ void f4arr(const float4 v, float* a) {
    a[0] = v.x; a[1] = v.y; a[2] = v.z; a[3] = v.w;
}

template<bool REC>
__global__ __launch_bounds__(256, 1)
void moe_kernel(const float* __restrict__ xsrc,   // REC ? result : data
                const float* __restrict__ We1, const float* __restrict__ be1,
                const float* __restrict__ We2, const float* __restrict__ be2,
                const float* __restrict__ Wg,  const float* __restrict__ bg,
                const float* __restrict__ Wr,  const float* __restrict__ br,
                const float* __restrict__ sbuf, // (B,) co0*gate, REC only
                float* __restrict__ result)     // (32768,128)
{
    extern __shared__ float lds[];
    float* xT  = lds;            // [256][68] k-major
    float* hT  = lds + 17408;    // [256][68] k-major (alias rT)
    float* WS  = lds + 34816;    // [16][256]
    float* gld = lds + 38912;    // [64][8]

    const int tid = threadIdx.x;
    const int mi  = tid >> 5;    // 0..7  -> rows mi*4..+3 and 32+mi*4..+3
    const int ci  = tid & 31;    // 0..31 -> cols ci*4(+128)
    const int n0  = blockIdx.x * 64;

    if (!REC) {
        // stage data tile (64x256) transposed into xT[k][m]
        #pragma unroll
        for (int i = 0; i < 16; ++i) {
            int m  = i * 4 + (tid >> 6);
            int k4 = (tid & 63) * 4;
            float4 v = *(const float4*)&xsrc[(size_t)(n0 + m) * 256 + k4];
            xT[(k4 + 0) * XT_STRIDE + m] = v.x;
            xT[(k4 + 1) * XT_STRIDE + m] = v.y;
            xT[(k4 + 2) * XT_STRIDE + m] = v.z;
            xT[(k4 + 3) * XT_STRIDE + m] = v.w;
        }
    } else {
        // stage result tile (64x128) transposed into rT[k][m] (alias hT)
        float* rT = hT;
        #pragma unroll
        for (int i = 0; i < 8; ++i) {
            int idx = i * 256 + tid;
            int m   = idx >> 5;
            int k4  = (idx & 31) * 4;
            float4 v = *(const float4*)&xsrc[(size_t)(n0 + m) * 128 + k4];
            rT[(k4 + 0) * XT_STRIDE + m] = v.x;
            rT[(k4 + 1) * XT_STRIDE + m] = v.y;
            rT[(k4 + 2) * XT_STRIDE + m] = v.z;
            rT[(k4 + 3) * XT_STRIDE + m] = v.w;
        }
        __syncthreads();
        // GEMM-r: x(64x256) = r(64x128) @ Wr(128x256) + br
        float acc[8][8] = {};
        #pragma unroll 1
        for (int kt = 0; kt < 8; ++kt) {
            __syncthreads();
            const float* src = Wr + kt * 4096;
            #pragma unroll
            for (int i = 0; i < 4; ++i)
                *(float4*)&WS[i * 1024 + tid * 4] =
                    *(const float4*)&src[i * 1024 + tid * 4];
            __syncthreads();
            #pragma unroll 8
            for (int k = 0; k < 16; ++k) {
                const float* rrow = &rT[(kt * 16 + k) * XT_STRIDE];
                float av[8], bv[8];
                f4arr(*(const float4*)&rrow[mi * 4], av);
                f4arr(*(const float4*)&rrow[32 + mi * 4], av + 4);
                f4arr(*(const float4*)&WS[k * 256 + ci * 4], bv);
                f4arr(*(const float4*)&WS[k * 256 + 128 + ci * 4], bv + 4);
                #pragma unroll
                for (int mm = 0; mm < 8; ++mm)
                    #pragma unroll
                    for (int cc = 0; cc < 8; ++cc)
                        acc[mm][cc] = fmaf(av[mm], bv[cc], acc[mm][cc]);
            }
        }
        // epilogue: + br, write x transposed into xT[d][m]
        float brv[8];
        #pragma unroll
        for (int j = 0; j < 8; ++j)
            brv[j] = br[ci * 4 + (j >> 2) * 128 + (j & 3)];
        #pragma unroll
        for (int j = 0; j < 8; ++j) {
            int d = ci * 4 + (j >> 2) * 128 + (j & 3);
            float4 lo, hi;
            lo.x = acc[0][j] + brv[j]; lo.y = acc[1][j] + brv[j];
            lo.z = acc[2][j] + brv[j]; lo.w = acc[3][j] + brv[j];
            hi.x = acc[4][j] + brv[j]; hi.y = acc[5][j] + brv[j];
            hi.z = acc[6][j] + brv[j]; hi.w = acc[7][j] + brv[j];
            *(float4*)&xT[d * XT_STRIDE + mi * 4]      = lo;
            *(float4*)&xT[d * XT_STRIDE + 32 + mi * 4] = hi;
        }
    }
    __syncthreads();

    // ---- gating: g = softmax(x @ Wg + bg) ----
    // stage Wg (256x8 = 2048 floats) into WS
    #pragma unroll
    for (int i = 0; i < 2; ++i)
        *(float4*)&WS[i * 1024 + tid * 4] = *(const float4*)&Wg[i * 1024 + tid * 4];
    __syncthreads();
    #pragma unroll
    for (int t2 = 0; t2 < 2; ++t2) {
        int idx = t2 * 256 + tid;
        int m = idx >> 3, e = idx & 7;
        float a = bg[e];
        #pragma unroll 8
        for (int k = 0; k < 256; ++k)
            a = fmaf(xT[k * XT_STRIDE + m], WS[k * 8 + e], a);
        gld[idx] = a;
    }
    __syncthreads();
    {
        float v0[8], v1[8];
        int m0g = tid >> 3, e0g = tid & 7;
        int m1g = 32 + (tid >> 3);
        #pragma unroll
        for (int j = 0; j < 8; ++j) { v0[j] = gld[m0g * 8 + j]; v1[j] = gld[m1g * 8 + j]; }
        __syncthreads();
        float mx0 = v0[0], mx1 = v1[0];
        #pragma unroll
        for (int j = 1; j < 8; ++j) { mx0 = fmaxf(mx0, v0[j]); mx1 = fmaxf(mx1, v1[j]); }
        float s0 = 0.f, s1 = 0.f;
        #pragma unroll
        for (int j = 0; j < 8; ++j) { s0 += __expf(v0[j] - mx0); s1 += __expf(v1[j] - mx1); }
        gld[tid]       = __expf(v0[e0g] - mx0) / s0;
        gld[tid + 256] = __expf(v1[e0g] - mx1) / s1;
        __syncthreads();
    }

    // ---- expert loop: out += g_e * (relu(x@We1_e+be1_e)@We2_e + be2_e) ----
    float out[8][4] = {};
    #pragma unroll 1
    for (int e = 0; e < 8; ++e) {
        // GEMM1: h(64x256) = relu(x @ We1[e] + be1[e])
        float acc[8][8] = {};
        const float* w1 = We1 + e * 65536;
        #pragma unroll 1
        for (int kt = 0; kt < 16; ++kt) {
            __syncthreads();
            #pragma unroll
            for (int i = 0; i < 4; ++i)
                *(float4*)&WS[i * 1024 + tid * 4] =
                    *(const float4*)&w1[kt * 4096 + i * 1024 + tid * 4];
            __syncthreads();
            #pragma unroll 8
            for (int k = 0; k < 16; ++k) {
                const float* xrow = &xT[(kt * 16 + k) * XT_STRIDE];
                float av[8], bv[8];
                f4arr(*(const float4*)&xrow[mi * 4], av);
                f4arr(*(const float4*)&xrow[32 + mi * 4], av + 4);
                f4arr(*(const float4*)&WS[k * 256 + ci * 4], bv);
                f4arr(*(const float4*)&WS[k * 256 + 128 + ci * 4], bv + 4);
                #pragma unroll
                for (int mm = 0; mm < 8; ++mm)
                    #pragma unroll
                    for (int cc = 0; cc < 8; ++cc)
                        acc[mm][cc] = fmaf(av[mm], bv[cc], acc[mm][cc]);
            }
        }
        // epilogue -> hT[c][m] (safe: all threads past last barrier are done
        // reading hT from previous expert's GEMM2)
        {
            float b1v[8];
            #pragma unroll
            for (int j = 0; j < 8; ++j)
                b1v[j] = be1[e * 256 + ci * 4 + (j >> 2) * 128 + (j & 3)];
            #pragma unroll
            for (int j = 0; j < 8; ++j) {
                int c = ci * 4 + (j >> 2) * 128 + (j & 3);
                float4 lo, hi;
                lo.x = fmaxf(acc[0][j] + b1v[j], 0.f);
                lo.y = fmaxf(acc[1][j] + b1v[j], 0.f);
                lo.z = fmaxf(acc[2][j] + b1v[j], 0.f);
                lo.w = fmaxf(acc[3][j] + b1v[j], 0.f);
                hi.x = fmaxf(acc[4][j] + b1v[j], 0.f);
                hi.y = fmaxf(acc[5][j] + b1v[j], 0.f);
                hi.z = fmaxf(acc[6][j] + b1v[j], 0.f);
                hi.w = fmaxf(acc[7][j] + b1v[j], 0.f);
                *(float4*)&hT[c * XT_STRIDE + mi * 4]      = lo;
                *(float4*)&hT[c * XT_STRIDE + 32 + mi * 4] = hi;
            }
        }
        // GEMM2: eo(64x128) = h @ We2[e]; out += g*(eo + be2)
        float acc2[8][4] = {};
        const float* w2 = We2 + e * 32768;
        #pragma unroll 1
        for (int kt = 0; kt < 16; ++kt) {
            __syncthreads();
            #pragma unroll
            for (int i = 0; i < 2; ++i)
                *(float4*)&WS[i * 1024 + tid * 4] =
                    *(const float4*)&w2[kt * 2048 + i * 1024 + tid * 4];
            __syncthreads();
            #pragma unroll 8
            for (int k = 0; k < 16; ++k) {
                const float* hrow = &hT[(kt * 16 + k) * XT_STRIDE];
                float av[8], bv[4];
                f4arr(*(const float4*)&hrow[mi * 4], av);
                f4arr(*(const float4*)&hrow[32 + mi * 4], av + 4);
                f4arr(*(const float4*)&WS[k * 128 + ci * 4], bv);
                #pragma unroll
                for (int mm = 0; mm < 8; ++mm)
                    #pragma unroll
                    for (int cc = 0; cc < 4; ++cc)
                        acc2[mm][cc] = fmaf(av[mm], bv[cc], acc2[mm][cc]);
            }
        }
        float b2v[4];
        #pragma unroll
        for (int cc = 0; cc < 4; ++cc) b2v[cc] = be2[e * 128 + ci * 4 + cc];
        #pragma unroll
        for (int mm = 0; mm < 8; ++mm) {
            int m = (mm < 4) ? (mi * 4 + mm) : (32 + mi * 4 + mm - 4);
            float gv = gld[m * 8 + e];
            #pragma unroll
            for (int cc = 0; cc < 4; ++cc)
                out[mm][cc] = fmaf(gv, acc2[mm][cc] + b2v[cc], out[mm][cc]);
        }
    }

    // ---- store: init -> result = out ; rec -> result += out * s[b] ----
    #pragma unroll
    for (int mm = 0; mm < 8; ++mm) {
        int m = (mm < 4) ? (mi * 4 + mm) : (32 + mi * 4 + mm - 4);
        int n = n0 + m;
        float4 o;
        o.x = out[mm][0]; o.y = out[mm][1]; o.z = out[mm][2]; o.w = out[mm][3];
        float* dst = result + (size_t)n * 128 + ci * 4;
        if (REC) {
            float sv = sbuf[n >> 2];
            float4 old = *(const float4*)dst;
            o.x = fmaf(o.x, sv, old.x);
            o.y = fmaf(o.y, sv, old.y);
            o.z = fmaf(o.z, sv, old.z);
            o.w = fmaf(o.w, sv, old.w);
        }
        *(float4*)dst = o;
    }
}

// ---------------- co / gate kernel ----------------
// one wave per sample; s[b] = co0 * (co0 > thresh)
__global__ __launch_bounds__(256)
void co_kernel(const float* __restrict__ result, const float* __restrict__ Wog,
               const float* __restrict__ bog, float* __restrict__ sbuf,
               float thresh)
{
    int lane = threadIdx.x & 63;
    int w    = threadIdx.x >> 6;
    int b    = blockIdx.x * 4 + w;
    const float* r = result + (size_t)b * 512;
    float l0 = 0.f, l1 = 0.f;
    #pragma unroll
    for (int j = 0; j < 8; ++j) {
        int d = j * 64 + lane;
        float rv = r[d];
        float2 wv = *(const float2*)&Wog[d * 2];
        l0 = fmaf(rv, wv.x, l0);
        l1 = fmaf(rv, wv.y, l1);
    }
    #pragma unroll
    for (int off = 32; off > 0; off >>= 1) {
        l0 += __shfl_down(l0, off);
        l1 += __shfl_down(l1, off);
    }
    if (lane == 0) {
        l0 += bog[0]; l1 += bog[1];
        float co0 = 1.f / (1.f + __expf(l1 - l0));   // == softmax[...,0]
        sbuf[b] = (co0 > thresh) ? co0 : 0.f;
    }
}

// ---------------- Q head kernel ----------------
// 32 samples/block; values = relu(result@Wq1+bq1)@Wq2+bq2
// LDS: rq[512][36] @0 (18432 fl, hq[32][516] aliased) | WS[16][512] @18432 (8192 fl)
__global__ __launch_bounds__(256, 1)
void q_kernel(const float* __restrict__ result,
              const float* __restrict__ Wq1, const float* __restrict__ bq1,
              const float* __restrict__ Wq2, const float* __restrict__ bq2,
              float* __restrict__ out)
{
    extern __shared__ float lds[];
    float* rq = lds;             // [512][36] k-major
    float* hq = lds;             // [32][516] alias (after GEMM1)
    float* WS = lds + 18432;     // [16][512]
    const int tid = threadIdx.x;
    const int mi  = tid >> 5, ci = tid & 31;
    const int n0  = blockIdx.x * 32;

    // stage result (32x512) transposed
    #pragma unroll
    for (int i = 0; i < 16; ++i) {
        int idx = i * 256 + tid;
        int m   = idx >> 7;
        int k4  = (idx & 127) * 4;
        float4 v = *(const float4*)&result[(size_t)(n0 + m) * 512 + k4];
        rq[(k4 + 0) * 36 + m] = v.x;
        rq[(k4 + 1) * 36 + m] = v.y;
        rq[(k4 + 2) * 36 + m] = v.z;
        rq[(k4 + 3) * 36 + m] = v.w;
    }

    // GEMM1: hid(32x512) = relu(r @ Wq1 + bq1); thread tile 4m x 16c
    float acc[4][16] = {};
    #pragma unroll 1
    for (int kt = 0; kt < 32; ++kt) {
        __syncthreads();
        #pragma unroll
        for (int i = 0; i < 8; ++i)
            *(float4*)&WS[i * 1024 + tid * 4] =
                *(const float4*)&Wq1[kt * 8192 + i * 1024 + tid * 4];
        __syncthreads();
        #pragma unroll 8
        for (int k = 0; k < 16; ++k) {
            float av[4];
            f4arr(*(const float4*)&rq[(kt * 16 + k) * 36 + mi * 4], av);
            #pragma unroll
            for (int j = 0; j < 4; ++j) {
                float bv[4];
                f4arr(*(const float4*)&WS[k * 512 + ci * 4 + j * 128], bv);
                #pragma unroll
                for (int mm = 0; mm < 4; ++mm)
                    #pragma unroll
                    for (int cc = 0; cc < 4; ++cc)
                        acc[mm][j * 4 + cc] = fmaf(av[mm], bv[cc], acc[mm][j * 4 + cc]);
            }
        }
    }
    __syncthreads();   // all rq reads complete before aliased hq writes
    #pragma unroll
    for (int j = 0; j < 4; ++j) {
        int c = ci * 4 + j * 128;
        float4 bb = *(const float4*)&bq1[c];
        #pragma unroll
        for (int mm = 0; mm < 4; ++mm) {
            float4 h;
            h.x = fmaxf(acc[mm][j * 4 + 0] + bb.x, 0.f);
            h.y = fmaxf(acc[mm][j * 4 + 1] + bb.y, 0.f);
            h.z = fmaxf(acc[mm][j * 4 + 2] + bb.z, 0.f);
            h.w = fmaxf(acc[mm][j * 4 + 3] + bb.w, 0.f);
            *(float4*)&hq[(mi * 4 + mm) * 516 + c] = h;
        }
    }
    __syncthreads();
    // GEMM2: values(32x18) = hid @ Wq2 + bq2
    for (int idx = tid; idx < 576; idx += 256) {
        int m = idx / 18, a = idx % 18;
        float s = bq2[a];
        #pragma unroll 8
        for (int k = 0; k < 512; ++k)
            s = fmaf(hq[m * 516 + k], Wq2[k * 18 + a], s);
        out[(size_t)(n0 + m) * 18 + a] = s;
    }
}

extern "C" void kernel_launch(void* const* d_in, const int* in_sizes, int n_in,
                              void* d_out, int out_size, void* d_ws, size_t ws_size,
                              hipStream_t stream)
{
    (void)in_sizes; (void)n_in; (void)out_size; (void)ws_size;
    const float* data = (const float*)d_in[0];
    const float* We1  = (const float*)d_in[1];
    const float* be1  = (const float*)d_in[2];
    const float* We2  = (const float*)d_in[3];
    const float* be2  = (const float*)d_in[4];
    const float* Wg   = (const float*)d_in[5];
    const float* bg   = (const float*)d_in[6];
    const float* Wog  = (const float*)d_in[7];
    const float* bog  = (const float*)d_in[8];
    const float* Wr   = (const float*)d_in[9];
    const float* br   = (const float*)d_in[10];
    const float* Wq1  = (const float*)d_in[11];
    const float* bq1  = (const float*)d_in[12];
    const float* Wq2  = (const float*)d_in[13];
    const float* bq2  = (const float*)d_in[14];
    float* outp = (float*)d_out;

    float* result = (float*)d_ws;                       // 32768*128 fp32
    float* sbuf   = result + (size_t)32768 * 128;       // 8192 fp32

    const int MOE_LDS = 39424 * 4;   // 157696 B
    const int Q_LDS   = 26624 * 4;   // 106496 B

    moe_kernel<false><<<512, 256, MOE_LDS, stream>>>(
        data, We1, be1, We2, be2, Wg, bg, Wr, br, nullptr, result);
    co_kernel<<<2048, 256, 0, stream>>>(result, Wog, bog, sbuf, 0.3f);
    moe_kernel<true><<<512, 256, MOE_LDS, stream>>>(
        result, We1, be1, We2, be2, Wg, bg, Wr, br, sbuf, result);
    co_kernel<<<2048, 256, 0, stream>>>(result, Wog, bog, sbuf, 0.5f);
    moe_kernel<true><<<512, 256, MOE_LDS, stream>>>(
        result, We1, be1, We2, be2, Wg, bg, Wr, br, sbuf, result);
    q_kernel<<<256, 256, Q_LDS, stream>>>(result, Wq1, bq1, Wq2, bq2, outp);
}

// Round 2
// 1032.777 us; speedup vs baseline: 3.1620x; 3.1620x over previous
//
#include <hip/hip_runtime.h>
#include <math.h>

// B=8192, C=4, D=256, E=8, H=256, O=128, AQ=18, HQ=512, N=B*C=32768
//
// Strategy: fp16-split (Ozaki) MFMA. Every fp32 value v is represented as
// hi = f16(v), lo = f16((v-hi)*4096). Products: hi*hi -> acc_m;
// lo*hi + hi*lo -> acc_c; recombine v = acc_m + acc_c/4096. Error ~2^-22
// per product (lo*lo dropped), fp32 MFMA accumulation => fp32-class results,
// safe for the co0>THRESH gate decisions.
// Weights are pre-split into B-fragment-major hi/lo arrays in ws (~4.4MB,
// L2-resident) and loaded straight from L2 into VGPRs -> no LDS staging and
// no __syncthreads inside any K-loop.

typedef _Float16 f16;
typedef f16   f16x8  __attribute__((ext_vector_type(8)));
typedef f16   f16x4  __attribute__((ext_vector_type(4)));
typedef float f32x16 __attribute__((ext_vector_type(16)));

#define MFMA(a, b, c) __builtin_amdgcn_mfma_f32_32x32x16_f16(a, b, c, 0, 0, 0)
#define LO_SCALE 4096.0f
#define LO_INV   (1.0f / 4096.0f)

#define XS 264   // half-stride of 256-wide LDS rows (528B: 16B-aligned)
#define RS 136   // half-stride of 128-wide LDS rows
#define QS 520   // half-stride of 512-wide LDS rows (q kernel)

// ---------------- weight prep: fp32 -> frag-major fp16 hi/lo ----------------
// One 64-lane wave per 32n x 16k fragment tile. Fragment layout (32x32x16):
// B[k][n]: n = lane&31, k = (lane>>5)*8 + j. Store: tile*512 + lane*8 + j.
__global__ __launch_bounds__(256) void prep_kernel(
    const float* __restrict__ We1, const float* __restrict__ We2,
    const float* __restrict__ Wr,  const float* __restrict__ Wg,
    const float* __restrict__ Wq1, const float* __restrict__ Wq2,
    f16* __restrict__ W1H, f16* __restrict__ W1L,
    f16* __restrict__ W2H, f16* __restrict__ W2L,
    f16* __restrict__ WrH, f16* __restrict__ WrL,
    f16* __restrict__ WgH, f16* __restrict__ WgL,
    f16* __restrict__ Wq1H, f16* __restrict__ Wq1L,
    f16* __restrict__ Wq2H, f16* __restrict__ Wq2L)
{
    int t = blockIdx.x * 4 + (threadIdx.x >> 6);
    int lane = threadIdx.x & 63;
    const float* src; f16 *dh, *dl;
    int stride, ncols, kbase, nbase, tile;
    if (t < 1024) {        // We1: (E,256,256) -> 8e x 16kt x 8nt
        int e = t >> 7, kt = (t >> 3) & 15, nt = t & 7;
        src = We1 + e * 65536; stride = 256; ncols = 256;
        kbase = kt * 16; nbase = nt * 32; tile = t; dh = W1H; dl = W1L;
    } else if (t < 1536) { // We2: (E,256,128) -> 8e x 16kt x 4nt
        int i = t - 1024; int e = i >> 6, kt = (i >> 2) & 15, nt = i & 3;
        src = We2 + e * 32768; stride = 128; ncols = 128;
        kbase = kt * 16; nbase = nt * 32; tile = i; dh = W2H; dl = W2L;
    } else if (t < 1600) { // Wr: (128,256) -> 8kt x 8nt
        int i = t - 1536; int kt = i >> 3, nt = i & 7;
        src = Wr; stride = 256; ncols = 256;
        kbase = kt * 16; nbase = nt * 32; tile = i; dh = WrH; dl = WrL;
    } else if (t < 1616) { // Wg: (256,8) pad n->32 -> 16kt x 1nt
        int i = t - 1600;
        src = Wg; stride = 8; ncols = 8;
        kbase = i * 16; nbase = 0; tile = i; dh = WgH; dl = WgL;
    } else if (t < 2128) { // Wq1: (512,512) -> 32kt x 16nt
        int i = t - 1616; int kt = i >> 4, nt = i & 15;
        src = Wq1; stride = 512; ncols = 512;
        kbase = kt * 16; nbase = nt * 32; tile = i; dh = Wq1H; dl = Wq1L;
    } else {               // Wq2: (512,18) pad n->32 -> 32kt x 1nt
        int i = t - 2128;
        src = Wq2; stride = 18; ncols = 18;
        kbase = i * 16; nbase = 0; tile = i; dh = Wq2H; dl = Wq2L;
    }
    int n = lane & 31, kg = lane >> 5;
    int col = nbase + n;
    f16x8 hv, lv;
    #pragma unroll
    for (int j = 0; j < 8; ++j) {
        int k = kbase + kg * 8 + j;
        float w = (col < ncols) ? src[(size_t)k * stride + col] : 0.f;
        f16 h = (f16)w;
        hv[j] = h;
        lv[j] = (f16)((w - (float)h) * LO_SCALE);
    }
    *(f16x8*)(dh + (size_t)tile * 512 + lane * 8) = hv;
    *(f16x8*)(dl + (size_t)tile * 512 + lane * 8) = lv;
}

// ---------------- fused MoE kernel (MFMA) ----------------
// 64 tokens/block, 512 threads = 8 waves.
// LDS: xh/xl [64][XS] halves, hh/hl [64][XS] (alias r staging at RS stride),
// gld float[64*8]. Total 137216 B.
template<bool REC>
__global__ __launch_bounds__(512, 1) void moe_mfma(
    const float* xsrc, const float* __restrict__ sbuf,
    const f16* __restrict__ W1H, const f16* __restrict__ W1L,
    const f16* __restrict__ W2H, const f16* __restrict__ W2L,
    const f16* __restrict__ WrH, const f16* __restrict__ WrL,
    const f16* __restrict__ WgH, const f16* __restrict__ WgL,
    const float* __restrict__ be1, const float* __restrict__ be2,
    const float* __restrict__ bg,  const float* __restrict__ br,
    float* result)
{
    extern __shared__ char smem[];
    f16* xh = (f16*)smem;
    f16* xl = xh + 64 * XS;
    f16* hh = xl + 64 * XS;
    f16* hl = hh + 64 * XS;
    float* gld = (float*)(hl + 64 * XS);   // [64][8]

    const int tid = threadIdx.x;
    const int lane = tid & 63;
    const int wv = tid >> 6;
    const int l31 = lane & 31;
    const int kg = lane >> 5;
    const int n0 = blockIdx.x * 64;

    if (!REC) {
        // stage x (64x256 fp32) -> split hi/lo rows
        #pragma unroll
        for (int i = 0; i < 8; ++i) {
            int idx = i * 512 + tid;
            int m = idx >> 6, k4 = (idx & 63) * 4;
            float4 v = *(const float4*)&xsrc[(size_t)(n0 + m) * 256 + k4];
            f16x4 hv, lv;
            hv[0] = (f16)v.x; lv[0] = (f16)((v.x - (float)hv[0]) * LO_SCALE);
            hv[1] = (f16)v.y; lv[1] = (f16)((v.y - (float)hv[1]) * LO_SCALE);
            hv[2] = (f16)v.z; lv[2] = (f16)((v.z - (float)hv[2]) * LO_SCALE);
            hv[3] = (f16)v.w; lv[3] = (f16)((v.w - (float)hv[3]) * LO_SCALE);
            *(f16x4*)&xh[m * XS + k4] = hv;
            *(f16x4*)&xl[m * XS + k4] = lv;
        }
    } else {
        // stage r = result rows (64x128) into hh/hl at stride RS
        #pragma unroll
        for (int i = 0; i < 4; ++i) {
            int idx = i * 512 + tid;
            int m = idx >> 5, k4 = (idx & 31) * 4;
            float4 v = *(const float4*)&xsrc[(size_t)(n0 + m) * 128 + k4];
            f16x4 hv, lv;
            hv[0] = (f16)v.x; lv[0] = (f16)((v.x - (float)hv[0]) * LO_SCALE);
            hv[1] = (f16)v.y; lv[1] = (f16)((v.y - (float)hv[1]) * LO_SCALE);
            hv[2] = (f16)v.z; lv[2] = (f16)((v.z - (float)hv[2]) * LO_SCALE);
            hv[3] = (f16)v.w; lv[3] = (f16)((v.w - (float)hv[3]) * LO_SCALE);
            *(f16x4*)&hh[m * RS + k4] = hv;
            *(f16x4*)&hl[m * RS + k4] = lv;
        }
        __syncthreads();
        // rec GEMM: x(64x256) = r(64x128) @ Wr + br
        f32x16 am0 = {}, ac0 = {}, am1 = {}, ac1 = {};
        int Mt = wv >> 2, nt0 = (wv & 3) * 2;
        #pragma unroll 4
        for (int kt = 0; kt < 8; ++kt) {
            f16x8 ah = *(const f16x8*)&hh[(Mt * 32 + l31) * RS + kt * 16 + kg * 8];
            f16x8 al = *(const f16x8*)&hl[(Mt * 32 + l31) * RS + kt * 16 + kg * 8];
            f16x8 b0h = *(const f16x8*)(WrH + (size_t)(kt * 8 + nt0) * 512 + lane * 8);
            f16x8 b0l = *(const f16x8*)(WrL + (size_t)(kt * 8 + nt0) * 512 + lane * 8);
            f16x8 b1h = *(const f16x8*)(WrH + (size_t)(kt * 8 + nt0 + 1) * 512 + lane * 8);
            f16x8 b1l = *(const f16x8*)(WrL + (size_t)(kt * 8 + nt0 + 1) * 512 + lane * 8);
            am0 = MFMA(ah, b0h, am0); ac0 = MFMA(al, b0h, ac0); ac0 = MFMA(ah, b0l, ac0);
            am1 = MFMA(ah, b1h, am1); ac1 = MFMA(al, b1h, ac1); ac1 = MFMA(ah, b1l, ac1);
        }
        // write x = acc + br, split hi/lo. (xh/xl region untouched so far)
        #pragma unroll
        for (int t = 0; t < 2; ++t) {
            int nt = nt0 + t;
            int col = nt * 32 + l31;
            float brv = br[col];
            #pragma unroll
            for (int r = 0; r < 16; ++r) {
                int row = (r & 3) + 8 * (r >> 2) + 4 * kg + Mt * 32;
                float v = (t ? am1[r] + ac1[r] * LO_INV : am0[r] + ac0[r] * LO_INV) + brv;
                f16 hv = (f16)v;
                xh[row * XS + col] = hv;
                xl[row * XS + col] = (f16)((v - (float)hv) * LO_SCALE);
            }
        }
    }
    __syncthreads();

    // ---- gating: g = softmax(x @ Wg + bg), waves 0-1 (Mt = wv) ----
    if (wv < 2) {
        f32x16 am = {}, ac = {};
        int Mt = wv;
        #pragma unroll 4
        for (int kt = 0; kt < 16; ++kt) {
            f16x8 ah = *(const f16x8*)&xh[(Mt * 32 + l31) * XS + kt * 16 + kg * 8];
            f16x8 al = *(const f16x8*)&xl[(Mt * 32 + l31) * XS + kt * 16 + kg * 8];
            f16x8 bh = *(const f16x8*)(WgH + (size_t)kt * 512 + lane * 8);
            f16x8 bl = *(const f16x8*)(WgL + (size_t)kt * 512 + lane * 8);
            am = MFMA(ah, bh, am); ac = MFMA(al, bh, ac); ac = MFMA(ah, bl, ac);
        }
        int e = l31;
        float bge = (e < 8) ? bg[e] : 0.f;
        #pragma unroll
        for (int r = 0; r < 16; ++r) {
            float lg = am[r] + ac[r] * LO_INV + bge;
            float mx = lg;
            #pragma unroll
            for (int d = 1; d < 8; d <<= 1) mx = fmaxf(mx, __shfl_xor(mx, d, 64));
            float ex = __expf(lg - mx);
            float s = ex;
            #pragma unroll
            for (int d = 1; d < 8; d <<= 1) s += __shfl_xor(s, d, 64);
            if (e < 8) {
                int row = (r & 3) + 8 * (r >> 2) + 4 * kg + Mt * 32;
                gld[row * 8 + e] = ex / s;
            }
        }
    }
    __syncthreads();

    // ---- expert loop ----
    f32x16 out = {};
    const int Mt1 = wv >> 2, nt0 = (wv & 3) * 2;   // GEMM1: 2x8 tiles
    const int Mt2 = wv >> 2, nt2 = wv & 3;         // GEMM2: 2x4 tiles
    #pragma unroll 1
    for (int e = 0; e < 8; ++e) {
        // GEMM1: h(64x256) = relu(x @ We1[e] + be1[e])
        f32x16 am0 = {}, ac0 = {}, am1 = {}, ac1 = {};
        const f16* w1h = W1H + (size_t)e * 65536;
        const f16* w1l = W1L + (size_t)e * 65536;
        #pragma unroll 4
        for (int kt = 0; kt < 16; ++kt) {
            f16x8 ah = *(const f16x8*)&xh[(Mt1 * 32 + l31) * XS + kt * 16 + kg * 8];
            f16x8 al = *(const f16x8*)&xl[(Mt1 * 32 + l31) * XS + kt * 16 + kg * 8];
            f16x8 b0h = *(const f16x8*)(w1h + (size_t)(kt * 8 + nt0) * 512 + lane * 8);
            f16x8 b0l = *(const f16x8*)(w1l + (size_t)(kt * 8 + nt0) * 512 + lane * 8);
            f16x8 b1h = *(const f16x8*)(w1h + (size_t)(kt * 8 + nt0 + 1) * 512 + lane * 8);
            f16x8 b1l = *(const f16x8*)(w1l + (size_t)(kt * 8 + nt0 + 1) * 512 + lane * 8);
            am0 = MFMA(ah, b0h, am0); ac0 = MFMA(al, b0h, ac0); ac0 = MFMA(ah, b0l, ac0);
            am1 = MFMA(ah, b1h, am1); ac1 = MFMA(al, b1h, ac1); ac1 = MFMA(ah, b1l, ac1);
        }
        __syncthreads();   // previous GEMM2 readers of hh/hl are done
        #pragma unroll
        for (int t = 0; t < 2; ++t) {
            int nt = nt0 + t;
            int col = nt * 32 + l31;
            float b1v = be1[e * 256 + col];
            #pragma unroll
            for (int r = 0; r < 16; ++r) {
                int row = (r & 3) + 8 * (r >> 2) + 4 * kg + Mt1 * 32;
                float v = (t ? am1[r] + ac1[r] * LO_INV : am0[r] + ac0[r] * LO_INV) + b1v;
                v = fmaxf(v, 0.f);
                f16 hv = (f16)v;
                hh[row * XS + col] = hv;
                hl[row * XS + col] = (f16)((v - (float)hv) * LO_SCALE);
            }
        }
        __syncthreads();
        // GEMM2: eo(64x128) = h @ We2[e]; out += g*(eo + be2)
        f32x16 am2 = {}, ac2 = {};
        const f16* w2h = W2H + (size_t)e * 32768;
        const f16* w2l = W2L + (size_t)e * 32768;
        #pragma unroll 4
        for (int kt = 0; kt < 16; ++kt) {
            f16x8 ah = *(const f16x8*)&hh[(Mt2 * 32 + l31) * XS + kt * 16 + kg * 8];
            f16x8 al = *(const f16x8*)&hl[(Mt2 * 32 + l31) * XS + kt * 16 + kg * 8];
            f16x8 bh = *(const f16x8*)(w2h + (size_t)(kt * 4 + nt2) * 512 + lane * 8);
            f16x8 bl = *(const f16x8*)(w2l + (size_t)(kt * 4 + nt2) * 512 + lane * 8);
            am2 = MFMA(ah, bh, am2); ac2 = MFMA(al, bh, ac2); ac2 = MFMA(ah, bl, ac2);
        }
        float be2v = be2[e * 128 + nt2 * 32 + l31];
        #pragma unroll
        for (int r = 0; r < 16; ++r) {
            int row = (r & 3) + 8 * (r >> 2) + 4 * kg + Mt2 * 32;
            float gv = gld[row * 8 + e];
            out[r] += gv * (am2[r] + ac2[r] * LO_INV + be2v);
        }
    }

    // ---- store ----
    int col = nt2 * 32 + l31;
    #pragma unroll
    for (int r = 0; r < 16; ++r) {
        int row = (r & 3) + 8 * (r >> 2) + 4 * kg + Mt2 * 32;
        size_t off = (size_t)(n0 + row) * 128 + col;
        float v = out[r];
        if (REC) {
            float sv = sbuf[(n0 + row) >> 2];
            v = result[off] + v * sv;
        }
        result[off] = v;
    }
}

// ---------------- co / gate kernel (fp32 VALU, tiny) ----------------
__global__ __launch_bounds__(256) void co_kernel(
    const float* __restrict__ result, const float* __restrict__ Wog,
    const float* __restrict__ bog, float* __restrict__ sbuf, float thresh)
{
    int lane = threadIdx.x & 63;
    int w = threadIdx.x >> 6;
    int b = blockIdx.x * 4 + w;
    const float* r = result + (size_t)b * 512;
    float l0 = 0.f, l1 = 0.f;
    #pragma unroll
    for (int j = 0; j < 8; ++j) {
        int d = j * 64 + lane;
        float rv = r[d];
        float2 wv = *(const float2*)&Wog[d * 2];
        l0 = fmaf(rv, wv.x, l0);
        l1 = fmaf(rv, wv.y, l1);
    }
    #pragma unroll
    for (int off = 32; off > 0; off >>= 1) {
        l0 += __shfl_down(l0, off);
        l1 += __shfl_down(l1, off);
    }
    if (lane == 0) {
        l0 += bog[0]; l1 += bog[1];
        float co0 = 1.f / (1.f + __expf(l1 - l0));
        sbuf[b] = (co0 > thresh) ? co0 : 0.f;
    }
}

// ---------------- Q head kernel (MFMA) ----------------
// 32 samples/block, 512 threads. values = relu(result@Wq1+bq1)@Wq2+bq2
__global__ __launch_bounds__(512, 1) void q_mfma(
    const float* __restrict__ result,
    const f16* __restrict__ Wq1H, const f16* __restrict__ Wq1L,
    const f16* __restrict__ Wq2H, const f16* __restrict__ Wq2L,
    const float* __restrict__ bq1, const float* __restrict__ bq2,
    float* __restrict__ out)
{
    extern __shared__ char smem[];
    f16* rh = (f16*)smem;              // [32][QS]
    f16* rl = rh + 32 * QS;
    f16* hh = rl + 32 * QS;
    f16* hl = hh + 32 * QS;
    float* part = (float*)(hl + 32 * QS);  // [4][1024]
    const int tid = threadIdx.x;
    const int lane = tid & 63;
    const int wv = tid >> 6;
    const int l31 = lane & 31;
    const int kg = lane >> 5;
    const int n0 = blockIdx.x * 32;

    // stage result rows (32x512) hi/lo
    #pragma unroll
    for (int i = 0; i < 8; ++i) {
        int idx = i * 512 + tid;
        int m = idx >> 7, k4 = (idx & 127) * 4;
        float4 v = *(const float4*)&result[(size_t)(n0 + m) * 512 + k4];
        f16x4 hv, lv;
        hv[0] = (f16)v.x; lv[0] = (f16)((v.x - (float)hv[0]) * LO_SCALE);
        hv[1] = (f16)v.y; lv[1] = (f16)((v.y - (float)hv[1]) * LO_SCALE);
        hv[2] = (f16)v.z; lv[2] = (f16)((v.z - (float)hv[2]) * LO_SCALE);
        hv[3] = (f16)v.w; lv[3] = (f16)((v.w - (float)hv[3]) * LO_SCALE);
        *(f16x4*)&rh[m * QS + k4] = hv;
        *(f16x4*)&rl[m * QS + k4] = lv;
    }
    __syncthreads();

    // GEMM1: hid(32x512) = relu(r @ Wq1 + bq1); 16 Ntiles / 8 waves
    f32x16 am0 = {}, ac0 = {}, am1 = {}, ac1 = {};
    const int nt0 = wv * 2;
    #pragma unroll 4
    for (int kt = 0; kt < 32; ++kt) {
        f16x8 ah = *(const f16x8*)&rh[l31 * QS + kt * 16 + kg * 8];
        f16x8 al = *(const f16x8*)&rl[l31 * QS + kt * 16 + kg * 8];
        f16x8 b0h = *(const f16x8*)(Wq1H + (size_t)(kt * 16 + nt0) * 512 + lane * 8);
        f16x8 b0l = *(const f16x8*)(Wq1L + (size_t)(kt * 16 + nt0) * 512 + lane * 8);
        f16x8 b1h = *(const f16x8*)(Wq1H + (size_t)(kt * 16 + nt0 + 1) * 512 + lane * 8);
        f16x8 b1l = *(const f16x8*)(Wq1L + (size_t)(kt * 16 + nt0 + 1) * 512 + lane * 8);
        am0 = MFMA(ah, b0h, am0); ac0 = MFMA(al, b0h, ac0); ac0 = MFMA(ah, b0l, ac0);
        am1 = MFMA(ah, b1h, am1); ac1 = MFMA(al, b1h, ac1); ac1 = MFMA(ah, b1l, ac1);
    }
    #pragma unroll
    for (int t = 0; t < 2; ++t) {
        int col = (nt0 + t) * 32 + l31;
        float b1v = bq1[col];
        #pragma unroll
        for (int r = 0; r < 16; ++r) {
            int row = (r & 3) + 8 * (r >> 2) + 4 * kg;
            float v = (t ? am1[r] + ac1[r] * LO_INV : am0[r] + ac0[r] * LO_INV) + b1v;
            v = fmaxf(v, 0.f);
            f16 hv = (f16)v;
            hh[row * QS + col] = hv;
            hl[row * QS + col] = (f16)((v - (float)hv) * LO_SCALE);
        }
    }
    __syncthreads();

    // GEMM2: values(32x18) = hid @ Wq2 + bq2; K split over waves 0-3
    if (wv < 4) {
        f32x16 am = {}, ac = {};
        #pragma unroll 4
        for (int k2 = 0; k2 < 8; ++k2) {
            int kt = wv * 8 + k2;
            f16x8 ah = *(const f16x8*)&hh[l31 * QS + kt * 16 + kg * 8];
            f16x8 al = *(const f16x8*)&hl[l31 * QS + kt * 16 + kg * 8];
            f16x8 bh = *(const f16x8*)(Wq2H + (size_t)kt * 512 + lane * 8);
            f16x8 bl = *(const f16x8*)(Wq2L + (size_t)kt * 512 + lane * 8);
            am = MFMA(ah, bh, am); ac = MFMA(al, bh, ac); ac = MFMA(ah, bl, ac);
        }
        #pragma unroll
        for (int r = 0; r < 16; ++r) {
            int row = (r & 3) + 8 * (r >> 2) + 4 * kg;
            part[wv * 1024 + row * 32 + l31] = am[r] + ac[r] * LO_INV;
        }
    }
    __syncthreads();
    for (int idx = tid; idx < 1024; idx += 512) {
        int row = idx >> 5, c = idx & 31;
        if (c < 18) {
            float s = part[idx] + part[1024 + idx] + part[2048 + idx] + part[3072 + idx]
                      + bq2[c];
            out[(size_t)(n0 + row) * 18 + c] = s;
        }
    }
}

extern "C" void kernel_launch(void* const* d_in, const int* in_sizes, int n_in,
                              void* d_out, int out_size, void* d_ws, size_t ws_size,
                              hipStream_t stream)
{
    (void)in_sizes; (void)n_in; (void)out_size; (void)ws_size;
    const float* data = (const float*)d_in[0];
    const float* We1  = (const float*)d_in[1];
    const float* be1  = (const float*)d_in[2];
    const float* We2  = (const float*)d_in[3];
    const float* be2  = (const float*)d_in[4];
    const float* Wg   = (const float*)d_in[5];
    const float* bg   = (const float*)d_in[6];
    const float* Wog  = (const float*)d_in[7];
    const float* bog  = (const float*)d_in[8];
    const float* Wr   = (const float*)d_in[9];
    const float* br   = (const float*)d_in[10];
    const float* Wq1  = (const float*)d_in[11];
    const float* bq1  = (const float*)d_in[12];
    const float* Wq2  = (const float*)d_in[13];
    const float* bq2  = (const float*)d_in[14];
    float* outp = (float*)d_out;

    float* result = (float*)d_ws;                         // 32768*128 fp32
    float* sbuf   = result + (size_t)32768 * 128;         // 8192 fp32
    f16* fb = (f16*)((char*)d_ws + 16809984);             // frag arrays base
    f16* W1H  = fb;
    f16* W1L  = fb + 524288;
    f16* W2H  = fb + 1048576;
    f16* W2L  = fb + 1310720;
    f16* WrH  = fb + 1572864;
    f16* WrL  = fb + 1605632;
    f16* WgH  = fb + 1638400;
    f16* WgL  = fb + 1646592;
    f16* Wq1H = fb + 1654784;
    f16* Wq1L = fb + 1916928;
    f16* Wq2H = fb + 2179072;
    f16* Wq2L = fb + 2195456;

    const int MOE_LDS = 4 * 64 * XS * 2 + 64 * 8 * 4;     // 137216 B
    const int Q_LDS   = 4 * 32 * QS * 2 + 4 * 1024 * 4;   // 149504 B

    prep_kernel<<<540, 256, 0, stream>>>(We1, We2, Wr, Wg, Wq1, Wq2,
        W1H, W1L, W2H, W2L, WrH, WrL, WgH, WgL, Wq1H, Wq1L, Wq2H, Wq2L);

    moe_mfma<false><<<512, 512, MOE_LDS, stream>>>(
        data, nullptr, W1H, W1L, W2H, W2L, WrH, WrL, WgH, WgL,
        be1, be2, bg, br, result);
    co_kernel<<<2048, 256, 0, stream>>>(result, Wog, bog, sbuf, 0.3f);
    moe_mfma<true><<<512, 512, MOE_LDS, stream>>>(
        result, sbuf, W1H, W1L, W2H, W2L, WrH, WrL, WgH, WgL,
        be1, be2, bg, br, result);
    co_kernel<<<2048, 256, 0, stream>>>(result, Wog, bog, sbuf, 0.5f);
    moe_mfma<true><<<512, 512, MOE_LDS, stream>>>(
        result, sbuf, W1H, W1L, W2H, W2L, WrH, WrL, WgH, WgL,
        be1, be2, bg, br, result);
    q_mfma<<<256, 512, Q_LDS, stream>>>(result, Wq1H, Wq1L, Wq2H, Wq2L,
        bq1, bq2, outp);
}

// Round 4
// 821.826 us; speedup vs baseline: 3.9736x; 1.2567x over previous
//
#include <hip/hip_runtime.h>
#include <math.h>

// B=8192, C=4, D=256, E=8, H=256, O=128, AQ=18, HQ=512, N=B*C=32768
//
// fp16-split (Ozaki) MFMA: v = hi + lo*2^-12, 3 MFMAs per product pair
// (hi*hi, lo*hi, hi*lo), fp32 accumulation -> ~2^-22 relative error, safe
// for the co0>THRESH gate decisions.
// R3 = R2 with compile fix: nontemporal builtins need clang ext_vector_type,
// not HIP_vector_type float4.
//  - GEMM1/rec retiled: wave w owns N-tile nt=w (unique B frags, M=64 per
//    wave) -> B-fragment L2 traffic halved, no cross-wave duplication.
//  - nontemporal loads/stores on all result/data streaming -> the 33MB
//    stream no longer evicts the ~3.2MB weight-frag arrays from per-XCD L2.
//  - full K-loop unroll + __launch_bounds__(512,2) -> deeper load hoisting.

typedef _Float16 f16;
typedef f16   f16x8  __attribute__((ext_vector_type(8)));
typedef f16   f16x4  __attribute__((ext_vector_type(4)));
typedef float f32x16 __attribute__((ext_vector_type(16)));
typedef float v4f    __attribute__((ext_vector_type(4)));

#define MFMA(a, b, c) __builtin_amdgcn_mfma_f32_32x32x16_f16(a, b, c, 0, 0, 0)
#define LO_SCALE 4096.0f
#define LO_INV   (1.0f / 4096.0f)

#define XS 264   // f16 stride of 256-wide LDS rows (528B, 16B-aligned)
#define RS 136   // f16 stride of 128-wide LDS rows
#define QS 520   // f16 stride of 512-wide LDS rows (q kernel)

__device__ __forceinline__ v4f nt_load4(const float* p) {
    return __builtin_nontemporal_load((const v4f*)p);
}

// ---------------- weight prep: fp32 -> frag-major fp16 hi/lo ----------------
// One 64-lane wave per 32n x 16k fragment tile. B[k][n]: n = lane&31,
// k = (lane>>5)*8 + j. Store: tile*512 + lane*8 + j.
__global__ __launch_bounds__(256) void prep_kernel(
    const float* __restrict__ We1, const float* __restrict__ We2,
    const float* __restrict__ Wr,  const float* __restrict__ Wg,
    const float* __restrict__ Wq1, const float* __restrict__ Wq2,
    f16* __restrict__ W1H, f16* __restrict__ W1L,
    f16* __restrict__ W2H, f16* __restrict__ W2L,
    f16* __restrict__ WrH, f16* __restrict__ WrL,
    f16* __restrict__ WgH, f16* __restrict__ WgL,
    f16* __restrict__ Wq1H, f16* __restrict__ Wq1L,
    f16* __restrict__ Wq2H, f16* __restrict__ Wq2L)
{
    int t = blockIdx.x * 4 + (threadIdx.x >> 6);
    int lane = threadIdx.x & 63;
    const float* src; f16 *dh, *dl;
    int stride, ncols, kbase, nbase, tile;
    if (t < 1024) {        // We1: (E,256,256) -> 8e x 16kt x 8nt
        int e = t >> 7, kt = (t >> 3) & 15, nt = t & 7;
        src = We1 + e * 65536; stride = 256; ncols = 256;
        kbase = kt * 16; nbase = nt * 32; tile = t; dh = W1H; dl = W1L;
    } else if (t < 1536) { // We2: (E,256,128) -> 8e x 16kt x 4nt
        int i = t - 1024; int e = i >> 6, kt = (i >> 2) & 15, nt = i & 3;
        src = We2 + e * 32768; stride = 128; ncols = 128;
        kbase = kt * 16; nbase = nt * 32; tile = i; dh = W2H; dl = W2L;
    } else if (t < 1600) { // Wr: (128,256) -> 8kt x 8nt
        int i = t - 1536; int kt = i >> 3, nt = i & 7;
        src = Wr; stride = 256; ncols = 256;
        kbase = kt * 16; nbase = nt * 32; tile = i; dh = WrH; dl = WrL;
    } else if (t < 1616) { // Wg: (256,8) pad n->32 -> 16kt x 1nt
        int i = t - 1600;
        src = Wg; stride = 8; ncols = 8;
        kbase = i * 16; nbase = 0; tile = i; dh = WgH; dl = WgL;
    } else if (t < 2128) { // Wq1: (512,512) -> 32kt x 16nt
        int i = t - 1616; int kt = i >> 4, nt = i & 15;
        src = Wq1; stride = 512; ncols = 512;
        kbase = kt * 16; nbase = nt * 32; tile = i; dh = Wq1H; dl = Wq1L;
    } else {               // Wq2: (512,18) pad n->32 -> 32kt x 1nt
        int i = t - 2128;
        src = Wq2; stride = 18; ncols = 18;
        kbase = i * 16; nbase = 0; tile = i; dh = Wq2H; dl = Wq2L;
    }
    int n = lane & 31, kg = lane >> 5;
    int col = nbase + n;
    f16x8 hv, lv;
    #pragma unroll
    for (int j = 0; j < 8; ++j) {
        int k = kbase + kg * 8 + j;
        float w = (col < ncols) ? src[(size_t)k * stride + col] : 0.f;
        f16 h = (f16)w;
        hv[j] = h;
        lv[j] = (f16)((w - (float)h) * LO_SCALE);
    }
    *(f16x8*)(dh + (size_t)tile * 512 + lane * 8) = hv;
    *(f16x8*)(dl + (size_t)tile * 512 + lane * 8) = lv;
}

// ---------------- fused MoE kernel (MFMA) ----------------
// 64 tokens/block, 512 threads = 8 waves.
// GEMM1 / rec-GEMM tiling: wave w -> unique N-tile nt=w, both M-tiles.
// GEMM2 tiling: Mt = wv>>2, nt = wv&3 (B dup x2, L1 absorbs).
template<bool REC>
__global__ __launch_bounds__(512, 2) void moe_mfma(
    const float* xsrc, const float* __restrict__ sbuf,
    const f16* __restrict__ W1H, const f16* __restrict__ W1L,
    const f16* __restrict__ W2H, const f16* __restrict__ W2L,
    const f16* __restrict__ WrH, const f16* __restrict__ WrL,
    const f16* __restrict__ WgH, const f16* __restrict__ WgL,
    const float* __restrict__ be1, const float* __restrict__ be2,
    const float* __restrict__ bg,  const float* __restrict__ br,
    float* result)
{
    extern __shared__ char smem[];
    f16* xh = (f16*)smem;
    f16* xl = xh + 64 * XS;
    f16* hh = xl + 64 * XS;
    f16* hl = hh + 64 * XS;
    float* gld = (float*)(hl + 64 * XS);   // [64][8]

    const int tid = threadIdx.x;
    const int lane = tid & 63;
    const int wv = tid >> 6;
    const int l31 = lane & 31;
    const int kg = lane >> 5;
    const int n0 = blockIdx.x * 64;

    if (!REC) {
        // stage x (64x256 fp32) -> split hi/lo rows
        #pragma unroll
        for (int i = 0; i < 8; ++i) {
            int idx = i * 512 + tid;
            int m = idx >> 6, k4 = (idx & 63) * 4;
            v4f v = nt_load4(&xsrc[(size_t)(n0 + m) * 256 + k4]);
            f16x4 hv, lv;
            #pragma unroll
            for (int j = 0; j < 4; ++j) {
                hv[j] = (f16)v[j];
                lv[j] = (f16)((v[j] - (float)hv[j]) * LO_SCALE);
            }
            *(f16x4*)&xh[m * XS + k4] = hv;
            *(f16x4*)&xl[m * XS + k4] = lv;
        }
    } else {
        // stage r = result rows (64x128) into hh/hl at stride RS
        #pragma unroll
        for (int i = 0; i < 4; ++i) {
            int idx = i * 512 + tid;
            int m = idx >> 5, k4 = (idx & 31) * 4;
            v4f v = nt_load4(&xsrc[(size_t)(n0 + m) * 128 + k4]);
            f16x4 hv, lv;
            #pragma unroll
            for (int j = 0; j < 4; ++j) {
                hv[j] = (f16)v[j];
                lv[j] = (f16)((v[j] - (float)hv[j]) * LO_SCALE);
            }
            *(f16x4*)&hh[m * RS + k4] = hv;
            *(f16x4*)&hl[m * RS + k4] = lv;
        }
        __syncthreads();
        // rec GEMM: x(64x256) = r(64x128) @ Wr + br; wave w -> nt=w
        f32x16 am0 = {}, ac0 = {}, am1 = {}, ac1 = {};
        const f16* wrh = WrH + (size_t)wv * 512 + lane * 8;
        const f16* wrl = WrL + (size_t)wv * 512 + lane * 8;
        #pragma unroll
        for (int kt = 0; kt < 8; ++kt) {
            f16x8 bh = *(const f16x8*)(wrh + kt * 4096);
            f16x8 bl = *(const f16x8*)(wrl + kt * 4096);
            f16x8 ah0 = *(const f16x8*)&hh[l31 * RS + kt * 16 + kg * 8];
            f16x8 al0 = *(const f16x8*)&hl[l31 * RS + kt * 16 + kg * 8];
            f16x8 ah1 = *(const f16x8*)&hh[(32 + l31) * RS + kt * 16 + kg * 8];
            f16x8 al1 = *(const f16x8*)&hl[(32 + l31) * RS + kt * 16 + kg * 8];
            am0 = MFMA(ah0, bh, am0); ac0 = MFMA(al0, bh, ac0); ac0 = MFMA(ah0, bl, ac0);
            am1 = MFMA(ah1, bh, am1); ac1 = MFMA(al1, bh, ac1); ac1 = MFMA(ah1, bl, ac1);
        }
        {
            int col = wv * 32 + l31;
            float brv = br[col];
            #pragma unroll
            for (int Mt = 0; Mt < 2; ++Mt) {
                #pragma unroll
                for (int r = 0; r < 16; ++r) {
                    int row = (r & 3) + 8 * (r >> 2) + 4 * kg + Mt * 32;
                    float v = (Mt ? am1[r] + ac1[r] * LO_INV
                                  : am0[r] + ac0[r] * LO_INV) + brv;
                    f16 hv = (f16)v;
                    xh[row * XS + col] = hv;
                    xl[row * XS + col] = (f16)((v - (float)hv) * LO_SCALE);
                }
            }
        }
    }
    __syncthreads();

    // ---- gating: g = softmax(x @ Wg + bg), waves 0-1 (Mt = wv) ----
    if (wv < 2) {
        f32x16 am = {}, ac = {};
        int Mt = wv;
        #pragma unroll
        for (int kt = 0; kt < 16; ++kt) {
            f16x8 ah = *(const f16x8*)&xh[(Mt * 32 + l31) * XS + kt * 16 + kg * 8];
            f16x8 al = *(const f16x8*)&xl[(Mt * 32 + l31) * XS + kt * 16 + kg * 8];
            f16x8 bh = *(const f16x8*)(WgH + (size_t)kt * 512 + lane * 8);
            f16x8 bl = *(const f16x8*)(WgL + (size_t)kt * 512 + lane * 8);
            am = MFMA(ah, bh, am); ac = MFMA(al, bh, ac); ac = MFMA(ah, bl, ac);
        }
        int e = l31;
        float bge = (e < 8) ? bg[e] : 0.f;
        #pragma unroll
        for (int r = 0; r < 16; ++r) {
            float lg = am[r] + ac[r] * LO_INV + bge;
            float mx = lg;
            #pragma unroll
            for (int d = 1; d < 8; d <<= 1) mx = fmaxf(mx, __shfl_xor(mx, d, 64));
            float ex = __expf(lg - mx);
            float s = ex;
            #pragma unroll
            for (int d = 1; d < 8; d <<= 1) s += __shfl_xor(s, d, 64);
            if (e < 8) {
                int row = (r & 3) + 8 * (r >> 2) + 4 * kg + Mt * 32;
                gld[row * 8 + e] = ex / s;
            }
        }
    }
    __syncthreads();

    // ---- expert loop ----
    f32x16 out = {};
    const int Mt2 = wv >> 2, nt2 = wv & 3;   // GEMM2 tiling
    #pragma unroll 1
    for (int e = 0; e < 8; ++e) {
        // GEMM1: h(64x256) = relu(x @ We1[e] + be1[e]); wave w -> nt=w, M=64
        f32x16 am0 = {}, ac0 = {}, am1 = {}, ac1 = {};
        const f16* w1h = W1H + (size_t)e * 65536 + wv * 512 + lane * 8;
        const f16* w1l = W1L + (size_t)e * 65536 + wv * 512 + lane * 8;
        #pragma unroll
        for (int kt = 0; kt < 16; ++kt) {
            f16x8 bh = *(const f16x8*)(w1h + kt * 4096);
            f16x8 bl = *(const f16x8*)(w1l + kt * 4096);
            f16x8 ah0 = *(const f16x8*)&xh[l31 * XS + kt * 16 + kg * 8];
            f16x8 al0 = *(const f16x8*)&xl[l31 * XS + kt * 16 + kg * 8];
            f16x8 ah1 = *(const f16x8*)&xh[(32 + l31) * XS + kt * 16 + kg * 8];
            f16x8 al1 = *(const f16x8*)&xl[(32 + l31) * XS + kt * 16 + kg * 8];
            am0 = MFMA(ah0, bh, am0); ac0 = MFMA(al0, bh, ac0); ac0 = MFMA(ah0, bl, ac0);
            am1 = MFMA(ah1, bh, am1); ac1 = MFMA(al1, bh, ac1); ac1 = MFMA(ah1, bl, ac1);
        }
        __syncthreads();   // previous GEMM2 readers of hh/hl are done
        {
            int col = wv * 32 + l31;
            float b1v = be1[e * 256 + col];
            #pragma unroll
            for (int Mt = 0; Mt < 2; ++Mt) {
                #pragma unroll
                for (int r = 0; r < 16; ++r) {
                    int row = (r & 3) + 8 * (r >> 2) + 4 * kg + Mt * 32;
                    float v = (Mt ? am1[r] + ac1[r] * LO_INV
                                  : am0[r] + ac0[r] * LO_INV) + b1v;
                    v = fmaxf(v, 0.f);
                    f16 hv = (f16)v;
                    hh[row * XS + col] = hv;
                    hl[row * XS + col] = (f16)((v - (float)hv) * LO_SCALE);
                }
            }
        }
        __syncthreads();
        // GEMM2: eo(64x128) = h @ We2[e]; out += g*(eo + be2)
        f32x16 am2 = {}, ac2 = {};
        const f16* w2h = W2H + (size_t)e * 32768 + nt2 * 512 + lane * 8;
        const f16* w2l = W2L + (size_t)e * 32768 + nt2 * 512 + lane * 8;
        #pragma unroll
        for (int kt = 0; kt < 16; ++kt) {
            f16x8 bh = *(const f16x8*)(w2h + kt * 2048);
            f16x8 bl = *(const f16x8*)(w2l + kt * 2048);
            f16x8 ah = *(const f16x8*)&hh[(Mt2 * 32 + l31) * XS + kt * 16 + kg * 8];
            f16x8 al = *(const f16x8*)&hl[(Mt2 * 32 + l31) * XS + kt * 16 + kg * 8];
            am2 = MFMA(ah, bh, am2); ac2 = MFMA(al, bh, ac2); ac2 = MFMA(ah, bl, ac2);
        }
        float be2v = be2[e * 128 + nt2 * 32 + l31];
        #pragma unroll
        for (int r = 0; r < 16; ++r) {
            int row = (r & 3) + 8 * (r >> 2) + 4 * kg + Mt2 * 32;
            float gv = gld[row * 8 + e];
            out[r] += gv * (am2[r] + ac2[r] * LO_INV + be2v);
        }
    }

    // ---- store (nontemporal; REC does read-modify-write) ----
    int col = nt2 * 32 + l31;
    #pragma unroll
    for (int r = 0; r < 16; ++r) {
        int row = (r & 3) + 8 * (r >> 2) + 4 * kg + Mt2 * 32;
        size_t off = (size_t)(n0 + row) * 128 + col;
        float v = out[r];
        if (REC) {
            float sv = sbuf[(n0 + row) >> 2];
            float old = __builtin_nontemporal_load(&result[off]);
            v = old + v * sv;
        }
        __builtin_nontemporal_store(v, &result[off]);
    }
}

// ---------------- co / gate kernel (fp32 VALU, tiny) ----------------
__global__ __launch_bounds__(256) void co_kernel(
    const float* __restrict__ result, const float* __restrict__ Wog,
    const float* __restrict__ bog, float* __restrict__ sbuf, float thresh)
{
    int lane = threadIdx.x & 63;
    int w = threadIdx.x >> 6;
    int b = blockIdx.x * 4 + w;
    const float* r = result + (size_t)b * 512;
    float l0 = 0.f, l1 = 0.f;
    #pragma unroll
    for (int j = 0; j < 8; ++j) {
        int d = j * 64 + lane;
        float rv = __builtin_nontemporal_load(&r[d]);
        float2 wv = *(const float2*)&Wog[d * 2];
        l0 = fmaf(rv, wv.x, l0);
        l1 = fmaf(rv, wv.y, l1);
    }
    #pragma unroll
    for (int off = 32; off > 0; off >>= 1) {
        l0 += __shfl_down(l0, off);
        l1 += __shfl_down(l1, off);
    }
    if (lane == 0) {
        l0 += bog[0]; l1 += bog[1];
        float co0 = 1.f / (1.f + __expf(l1 - l0));
        sbuf[b] = (co0 > thresh) ? co0 : 0.f;
    }
}

// ---------------- Q head kernel (MFMA) ----------------
// 32 samples/block, 512 threads. values = relu(result@Wq1+bq1)@Wq2+bq2
__global__ __launch_bounds__(512, 2) void q_mfma(
    const float* __restrict__ result,
    const f16* __restrict__ Wq1H, const f16* __restrict__ Wq1L,
    const f16* __restrict__ Wq2H, const f16* __restrict__ Wq2L,
    const float* __restrict__ bq1, const float* __restrict__ bq2,
    float* __restrict__ out)
{
    extern __shared__ char smem[];
    f16* rh = (f16*)smem;              // [32][QS]
    f16* rl = rh + 32 * QS;
    f16* hh = rl + 32 * QS;
    f16* hl = hh + 32 * QS;
    float* part = (float*)(hl + 32 * QS);  // [4][1024]
    const int tid = threadIdx.x;
    const int lane = tid & 63;
    const int wv = tid >> 6;
    const int l31 = lane & 31;
    const int kg = lane >> 5;
    const int n0 = blockIdx.x * 32;

    // stage result rows (32x512) hi/lo
    #pragma unroll
    for (int i = 0; i < 8; ++i) {
        int idx = i * 512 + tid;
        int m = idx >> 7, k4 = (idx & 127) * 4;
        v4f v = nt_load4(&result[(size_t)(n0 + m) * 512 + k4]);
        f16x4 hv, lv;
        #pragma unroll
        for (int j = 0; j < 4; ++j) {
            hv[j] = (f16)v[j];
            lv[j] = (f16)((v[j] - (float)hv[j]) * LO_SCALE);
        }
        *(f16x4*)&rh[m * QS + k4] = hv;
        *(f16x4*)&rl[m * QS + k4] = lv;
    }
    __syncthreads();

    // GEMM1: hid(32x512) = relu(r @ Wq1 + bq1); 16 Ntiles / 8 waves
    f32x16 am0 = {}, ac0 = {}, am1 = {}, ac1 = {};
    const int nt0 = wv * 2;
    #pragma unroll
    for (int kt = 0; kt < 32; ++kt) {
        f16x8 ah = *(const f16x8*)&rh[l31 * QS + kt * 16 + kg * 8];
        f16x8 al = *(const f16x8*)&rl[l31 * QS + kt * 16 + kg * 8];
        f16x8 b0h = *(const f16x8*)(Wq1H + (size_t)(kt * 16 + nt0) * 512 + lane * 8);
        f16x8 b0l = *(const f16x8*)(Wq1L + (size_t)(kt * 16 + nt0) * 512 + lane * 8);
        f16x8 b1h = *(const f16x8*)(Wq1H + (size_t)(kt * 16 + nt0 + 1) * 512 + lane * 8);
        f16x8 b1l = *(const f16x8*)(Wq1L + (size_t)(kt * 16 + nt0 + 1) * 512 + lane * 8);
        am0 = MFMA(ah, b0h, am0); ac0 = MFMA(al, b0h, ac0); ac0 = MFMA(ah, b0l, ac0);
        am1 = MFMA(ah, b1h, am1); ac1 = MFMA(al, b1h, ac1); ac1 = MFMA(ah, b1l, ac1);
    }
    #pragma unroll
    for (int t = 0; t < 2; ++t) {
        int col = (nt0 + t) * 32 + l31;
        float b1v = bq1[col];
        #pragma unroll
        for (int r = 0; r < 16; ++r) {
            int row = (r & 3) + 8 * (r >> 2) + 4 * kg;
            float v = (t ? am1[r] + ac1[r] * LO_INV : am0[r] + ac0[r] * LO_INV) + b1v;
            v = fmaxf(v, 0.f);
            f16 hv = (f16)v;
            hh[row * QS + col] = hv;
            hl[row * QS + col] = (f16)((v - (float)hv) * LO_SCALE);
        }
    }
    __syncthreads();

    // GEMM2: values(32x18) = hid @ Wq2 + bq2; K split over waves 0-3
    if (wv < 4) {
        f32x16 am = {}, ac = {};
        #pragma unroll
        for (int k2 = 0; k2 < 8; ++k2) {
            int kt = wv * 8 + k2;
            f16x8 ah = *(const f16x8*)&hh[l31 * QS + kt * 16 + kg * 8];
            f16x8 al = *(const f16x8*)&hl[l31 * QS + kt * 16 + kg * 8];
            f16x8 bh = *(const f16x8*)(Wq2H + (size_t)kt * 512 + lane * 8);
            f16x8 bl = *(const f16x8*)(Wq2L + (size_t)kt * 512 + lane * 8);
            am = MFMA(ah, bh, am); ac = MFMA(al, bh, ac); ac = MFMA(ah, bl, ac);
        }
        #pragma unroll
        for (int r = 0; r < 16; ++r) {
            int row = (r & 3) + 8 * (r >> 2) + 4 * kg;
            part[wv * 1024 + row * 32 + l31] = am[r] + ac[r] * LO_INV;
        }
    }
    __syncthreads();
    for (int idx = tid; idx < 1024; idx += 512) {
        int row = idx >> 5, c = idx & 31;
        if (c < 18) {
            float s = part[idx] + part[1024 + idx] + part[2048 + idx] + part[3072 + idx]
                      + bq2[c];
            out[(size_t)(n0 + row) * 18 + c] = s;
        }
    }
}

extern "C" void kernel_launch(void* const* d_in, const int* in_sizes, int n_in,
                              void* d_out, int out_size, void* d_ws, size_t ws_size,
                              hipStream_t stream)
{
    (void)in_sizes; (void)n_in; (void)out_size; (void)ws_size;
    const float* data = (const float*)d_in[0];
    const float* We1  = (const float*)d_in[1];
    const float* be1  = (const float*)d_in[2];
    const float* We2  = (const float*)d_in[3];
    const float* be2  = (const float*)d_in[4];
    const float* Wg   = (const float*)d_in[5];
    const float* bg   = (const float*)d_in[6];
    const float* Wog  = (const float*)d_in[7];
    const float* bog  = (const float*)d_in[8];
    const float* Wr   = (const float*)d_in[9];
    const float* br   = (const float*)d_in[10];
    const float* Wq1  = (const float*)d_in[11];
    const float* bq1  = (const float*)d_in[12];
    const float* Wq2  = (const float*)d_in[13];
    const float* bq2  = (const float*)d_in[14];
    float* outp = (float*)d_out;

    float* result = (float*)d_ws;                         // 32768*128 fp32
    float* sbuf   = result + (size_t)32768 * 128;         // 8192 fp32
    f16* fb = (f16*)((char*)d_ws + 16809984);             // frag arrays base
    f16* W1H  = fb;
    f16* W1L  = fb + 524288;
    f16* W2H  = fb + 1048576;
    f16* W2L  = fb + 1310720;
    f16* WrH  = fb + 1572864;
    f16* WrL  = fb + 1605632;
    f16* WgH  = fb + 1638400;
    f16* WgL  = fb + 1646592;
    f16* Wq1H = fb + 1654784;
    f16* Wq1L = fb + 1916928;
    f16* Wq2H = fb + 2179072;
    f16* Wq2L = fb + 2195456;

    const int MOE_LDS = 4 * 64 * XS * 2 + 64 * 8 * 4;     // 137216 B
    const int Q_LDS   = 4 * 32 * QS * 2 + 4 * 1024 * 4;   // 149504 B

    prep_kernel<<<540, 256, 0, stream>>>(We1, We2, Wr, Wg, Wq1, Wq2,
        W1H, W1L, W2H, W2L, WrH, WrL, WgH, WgL, Wq1H, Wq1L, Wq2H, Wq2L);

    moe_mfma<false><<<512, 512, MOE_LDS, stream>>>(
        data, nullptr, W1H, W1L, W2H, W2L, WrH, WrL, WgH, WgL,
        be1, be2, bg, br, result);
    co_kernel<<<2048, 256, 0, stream>>>(result, Wog, bog, sbuf, 0.3f);
    moe_mfma<true><<<512, 512, MOE_LDS, stream>>>(
        result, sbuf, W1H, W1L, W2H, W2L, WrH, WrL, WgH, WgL,
        be1, be2, bg, br, result);
    co_kernel<<<2048, 256, 0, stream>>>(result, Wog, bog, sbuf, 0.5f);
    moe_mfma<true><<<512, 512, MOE_LDS, stream>>>(
        result, sbuf, W1H, W1L, W2H, W2L, WrH, WrL, WgH, WgL,
        be1, be2, bg, br, result);
    q_mfma<<<256, 512, Q_LDS, stream>>>(result, Wq1H, Wq1L, Wq2H, Wq2L,
        bq1, bq2, outp);
}

// Round 5
// 739.541 us; speedup vs baseline: 4.4157x; 1.1113x over previous
//
#include <hip/hip_runtime.h>
#include <math.h>

// B=8192, C=4, D=256, E=8, H=256, O=128, AQ=18, HQ=512, N=B*C=32768
//
// fp16-split (Ozaki) MFMA: v = hi + lo*2^-12, 3 MFMAs per product pair,
// fp32 accumulation -> ~2^-22 relative error, safe for co0>THRESH gates.
// R4 changes vs R3 (latency/barrier-bound diagnosis):
//  - moe blocks: 512thr/64tok -> 256thr/32tok, LDS 137KB -> 67.6KB
//    => 2 independent blocks/CU (two barrier domains fill each other's
//    stalls; same wave count).
//  - split correction accumulators (aca+acb) -> halved MFMA dep chains.
//  - gating computed redundantly by every wave, g broadcast via __shfl
//    from the gating C-tile -> no gld LDS round-trip/ordering.
//  - GEMM1: 1 M-tile x 2 N-tiles per wave -> 2 LDS A-reads per 6 MFMAs.

typedef _Float16 f16;
typedef f16   f16x8  __attribute__((ext_vector_type(8)));
typedef f16   f16x4  __attribute__((ext_vector_type(4)));
typedef float f32x16 __attribute__((ext_vector_type(16)));
typedef float v4f    __attribute__((ext_vector_type(4)));

#define MFMA(a, b, c) __builtin_amdgcn_mfma_f32_32x32x16_f16(a, b, c, 0, 0, 0)
#define LO_SCALE 4096.0f
#define LO_INV   (1.0f / 4096.0f)

#define XS 264   // f16 stride of 256-wide LDS rows (528B, 16B-aligned)
#define RS 136   // f16 stride of 128-wide LDS rows
#define QS 520   // f16 stride of 512-wide LDS rows (q kernel)

__device__ __forceinline__ v4f nt_load4(const float* p) {
    return __builtin_nontemporal_load((const v4f*)p);
}

// ---------------- weight prep: fp32 -> frag-major fp16 hi/lo ----------------
// One 64-lane wave per 32n x 16k fragment tile. B[k][n]: n = lane&31,
// k = (lane>>5)*8 + j. Store: tile*512 + lane*8 + j.
__global__ __launch_bounds__(256) void prep_kernel(
    const float* __restrict__ We1, const float* __restrict__ We2,
    const float* __restrict__ Wr,  const float* __restrict__ Wg,
    const float* __restrict__ Wq1, const float* __restrict__ Wq2,
    f16* __restrict__ W1H, f16* __restrict__ W1L,
    f16* __restrict__ W2H, f16* __restrict__ W2L,
    f16* __restrict__ WrH, f16* __restrict__ WrL,
    f16* __restrict__ WgH, f16* __restrict__ WgL,
    f16* __restrict__ Wq1H, f16* __restrict__ Wq1L,
    f16* __restrict__ Wq2H, f16* __restrict__ Wq2L)
{
    int t = blockIdx.x * 4 + (threadIdx.x >> 6);
    int lane = threadIdx.x & 63;
    const float* src; f16 *dh, *dl;
    int stride, ncols, kbase, nbase, tile;
    if (t < 1024) {        // We1: (E,256,256) -> 8e x 16kt x 8nt
        int e = t >> 7, kt = (t >> 3) & 15, nt = t & 7;
        src = We1 + e * 65536; stride = 256; ncols = 256;
        kbase = kt * 16; nbase = nt * 32; tile = t; dh = W1H; dl = W1L;
    } else if (t < 1536) { // We2: (E,256,128) -> 8e x 16kt x 4nt
        int i = t - 1024; int e = i >> 6, kt = (i >> 2) & 15, nt = i & 3;
        src = We2 + e * 32768; stride = 128; ncols = 128;
        kbase = kt * 16; nbase = nt * 32; tile = i; dh = W2H; dl = W2L;
    } else if (t < 1600) { // Wr: (128,256) -> 8kt x 8nt
        int i = t - 1536; int kt = i >> 3, nt = i & 7;
        src = Wr; stride = 256; ncols = 256;
        kbase = kt * 16; nbase = nt * 32; tile = i; dh = WrH; dl = WrL;
    } else if (t < 1616) { // Wg: (256,8) pad n->32 -> 16kt x 1nt
        int i = t - 1600;
        src = Wg; stride = 8; ncols = 8;
        kbase = i * 16; nbase = 0; tile = i; dh = WgH; dl = WgL;
    } else if (t < 2128) { // Wq1: (512,512) -> 32kt x 16nt
        int i = t - 1616; int kt = i >> 4, nt = i & 15;
        src = Wq1; stride = 512; ncols = 512;
        kbase = kt * 16; nbase = nt * 32; tile = i; dh = Wq1H; dl = Wq1L;
    } else {               // Wq2: (512,18) pad n->32 -> 32kt x 1nt
        int i = t - 2128;
        src = Wq2; stride = 18; ncols = 18;
        kbase = i * 16; nbase = 0; tile = i; dh = Wq2H; dl = Wq2L;
    }
    int n = lane & 31, kg = lane >> 5;
    int col = nbase + n;
    f16x8 hv, lv;
    #pragma unroll
    for (int j = 0; j < 8; ++j) {
        int k = kbase + kg * 8 + j;
        float w = (col < ncols) ? src[(size_t)k * stride + col] : 0.f;
        f16 h = (f16)w;
        hv[j] = h;
        lv[j] = (f16)((w - (float)h) * LO_SCALE);
    }
    *(f16x8*)(dh + (size_t)tile * 512 + lane * 8) = hv;
    *(f16x8*)(dl + (size_t)tile * 512 + lane * 8) = lv;
}

// ---------------- fused MoE kernel (MFMA) ----------------
// 32 tokens/block, 256 threads = 4 waves, 1024 blocks, 2 blocks/CU.
// GEMM1/rec: wave w -> N-tiles {2w, 2w+1}, single M-tile (32 tokens).
// GEMM2: wave w -> N-tile w. Gating: all waves redundant, g via shfl.
template<bool REC>
__global__ __launch_bounds__(256, 2) void moe_mfma(
    const float* xsrc, const float* __restrict__ sbuf,
    const f16* __restrict__ W1H, const f16* __restrict__ W1L,
    const f16* __restrict__ W2H, const f16* __restrict__ W2L,
    const f16* __restrict__ WrH, const f16* __restrict__ WrL,
    const f16* __restrict__ WgH, const f16* __restrict__ WgL,
    const float* __restrict__ be1, const float* __restrict__ be2,
    const float* __restrict__ bg,  const float* __restrict__ br,
    float* result)
{
    extern __shared__ char smem[];
    f16* xh = (f16*)smem;              // [32][XS]
    f16* xl = xh + 32 * XS;
    f16* hh = xl + 32 * XS;            // [32][XS]; rec stages r at stride RS
    f16* hl = hh + 32 * XS;

    const int tid = threadIdx.x;
    const int lane = tid & 63;
    const int wv = tid >> 6;           // 0..3
    const int l31 = lane & 31;
    const int kg = lane >> 5;
    const int n0 = blockIdx.x * 32;

    if (!REC) {
        // stage x (32x256 fp32) -> split hi/lo rows
        #pragma unroll
        for (int i = 0; i < 8; ++i) {
            int idx = i * 256 + tid;
            int m = idx >> 6, k4 = (idx & 63) * 4;
            v4f v = nt_load4(&xsrc[(size_t)(n0 + m) * 256 + k4]);
            f16x4 hv, lv;
            #pragma unroll
            for (int j = 0; j < 4; ++j) {
                hv[j] = (f16)v[j];
                lv[j] = (f16)((v[j] - (float)hv[j]) * LO_SCALE);
            }
            *(f16x4*)&xh[m * XS + k4] = hv;
            *(f16x4*)&xl[m * XS + k4] = lv;
        }
    } else {
        // stage r = result rows (32x128) into hh/hl at stride RS
        #pragma unroll
        for (int i = 0; i < 4; ++i) {
            int idx = i * 256 + tid;
            int m = idx >> 5, k4 = (idx & 31) * 4;
            v4f v = nt_load4(&xsrc[(size_t)(n0 + m) * 128 + k4]);
            f16x4 hv, lv;
            #pragma unroll
            for (int j = 0; j < 4; ++j) {
                hv[j] = (f16)v[j];
                lv[j] = (f16)((v[j] - (float)hv[j]) * LO_SCALE);
            }
            *(f16x4*)&hh[m * RS + k4] = hv;
            *(f16x4*)&hl[m * RS + k4] = lv;
        }
        __syncthreads();
        // rec GEMM: x(32x256) = r(32x128) @ Wr + br; wave w -> nt {2w,2w+1}
        f32x16 am0 = {}, a0a = {}, a0b = {}, am1 = {}, a1a = {}, a1b = {};
        const f16* wrh = WrH + (size_t)(2 * wv) * 512 + lane * 8;
        const f16* wrl = WrL + (size_t)(2 * wv) * 512 + lane * 8;
        #pragma unroll
        for (int kt = 0; kt < 8; ++kt) {
            f16x8 b0h = *(const f16x8*)(wrh + (size_t)kt * 4096);
            f16x8 b0l = *(const f16x8*)(wrl + (size_t)kt * 4096);
            f16x8 b1h = *(const f16x8*)(wrh + (size_t)kt * 4096 + 512);
            f16x8 b1l = *(const f16x8*)(wrl + (size_t)kt * 4096 + 512);
            f16x8 ah = *(const f16x8*)&hh[l31 * RS + kt * 16 + kg * 8];
            f16x8 al = *(const f16x8*)&hl[l31 * RS + kt * 16 + kg * 8];
            am0 = MFMA(ah, b0h, am0); a0a = MFMA(al, b0h, a0a); a0b = MFMA(ah, b0l, a0b);
            am1 = MFMA(ah, b1h, am1); a1a = MFMA(al, b1h, a1a); a1b = MFMA(ah, b1l, a1b);
        }
        #pragma unroll
        for (int t = 0; t < 2; ++t) {
            int col = (2 * wv + t) * 32 + l31;
            float brv = br[col];
            #pragma unroll
            for (int r = 0; r < 16; ++r) {
                int row = (r & 3) + 8 * (r >> 2) + 4 * kg;
                float v = (t ? am1[r] + (a1a[r] + a1b[r]) * LO_INV
                             : am0[r] + (a0a[r] + a0b[r]) * LO_INV) + brv;
                f16 hv = (f16)v;
                xh[row * XS + col] = hv;
                xl[row * XS + col] = (f16)((v - (float)hv) * LO_SCALE);
            }
        }
    }
    __syncthreads();

    // ---- gating (all waves redundant): logits = x @ Wg + bg ----
    float gr[16];
    {
        f32x16 gm = {}, ga = {}, gb = {};
        #pragma unroll
        for (int kt = 0; kt < 16; ++kt) {
            f16x8 ah = *(const f16x8*)&xh[l31 * XS + kt * 16 + kg * 8];
            f16x8 al = *(const f16x8*)&xl[l31 * XS + kt * 16 + kg * 8];
            f16x8 bh = *(const f16x8*)(WgH + (size_t)kt * 512 + lane * 8);
            f16x8 bl = *(const f16x8*)(WgL + (size_t)kt * 512 + lane * 8);
            gm = MFMA(ah, bh, gm); ga = MFMA(al, bh, ga); gb = MFMA(ah, bl, gb);
        }
        float bge = (l31 < 8) ? bg[l31] : 0.f;
        #pragma unroll
        for (int r = 0; r < 16; ++r) {
            float lg = gm[r] + (ga[r] + gb[r]) * LO_INV + bge;
            float mx = lg;
            #pragma unroll
            for (int d = 1; d < 8; d <<= 1) mx = fmaxf(mx, __shfl_xor(mx, d, 64));
            float ex = __expf(lg - mx);
            float s = ex;
            #pragma unroll
            for (int d = 1; d < 8; d <<= 1) s += __shfl_xor(s, d, 64);
            gr[r] = ex / s;   // valid on lanes l31<8 (e=l31); others unused
        }
    }

    // ---- expert loop ----
    f32x16 out = {};
    #pragma unroll 1
    for (int e = 0; e < 8; ++e) {
        // GEMM1: h(32x256) = relu(x @ We1[e] + be1[e]); wave w -> nt {2w,2w+1}
        f32x16 am0 = {}, a0a = {}, a0b = {}, am1 = {}, a1a = {}, a1b = {};
        const f16* w1h = W1H + (size_t)e * 65536 + (2 * wv) * 512 + lane * 8;
        const f16* w1l = W1L + (size_t)e * 65536 + (2 * wv) * 512 + lane * 8;
        #pragma unroll
        for (int kt = 0; kt < 16; ++kt) {
            f16x8 b0h = *(const f16x8*)(w1h + (size_t)kt * 4096);
            f16x8 b0l = *(const f16x8*)(w1l + (size_t)kt * 4096);
            f16x8 b1h = *(const f16x8*)(w1h + (size_t)kt * 4096 + 512);
            f16x8 b1l = *(const f16x8*)(w1l + (size_t)kt * 4096 + 512);
            f16x8 ah = *(const f16x8*)&xh[l31 * XS + kt * 16 + kg * 8];
            f16x8 al = *(const f16x8*)&xl[l31 * XS + kt * 16 + kg * 8];
            am0 = MFMA(ah, b0h, am0); a0a = MFMA(al, b0h, a0a); a0b = MFMA(ah, b0l, a0b);
            am1 = MFMA(ah, b1h, am1); a1a = MFMA(al, b1h, a1a); a1b = MFMA(ah, b1l, a1b);
        }
        __syncthreads();   // previous GEMM2 readers of hh/hl are done
        #pragma unroll
        for (int t = 0; t < 2; ++t) {
            int col = (2 * wv + t) * 32 + l31;
            float b1v = be1[e * 256 + col];
            #pragma unroll
            for (int r = 0; r < 16; ++r) {
                int row = (r & 3) + 8 * (r >> 2) + 4 * kg;
                float v = (t ? am1[r] + (a1a[r] + a1b[r]) * LO_INV
                             : am0[r] + (a0a[r] + a0b[r]) * LO_INV) + b1v;
                v = fmaxf(v, 0.f);
                f16 hv = (f16)v;
                hh[row * XS + col] = hv;
                hl[row * XS + col] = (f16)((v - (float)hv) * LO_SCALE);
            }
        }
        __syncthreads();
        // GEMM2: eo(32x128) = h @ We2[e]; out += g_e*(eo + be2)
        f32x16 am2 = {}, a2a = {}, a2b = {};
        const f16* w2h = W2H + (size_t)e * 32768 + wv * 512 + lane * 8;
        const f16* w2l = W2L + (size_t)e * 32768 + wv * 512 + lane * 8;
        #pragma unroll
        for (int kt = 0; kt < 16; ++kt) {
            f16x8 bh = *(const f16x8*)(w2h + (size_t)kt * 2048);
            f16x8 bl = *(const f16x8*)(w2l + (size_t)kt * 2048);
            f16x8 ah = *(const f16x8*)&hh[l31 * XS + kt * 16 + kg * 8];
            f16x8 al = *(const f16x8*)&hl[l31 * XS + kt * 16 + kg * 8];
            am2 = MFMA(ah, bh, am2); a2a = MFMA(al, bh, a2a); a2b = MFMA(ah, bl, a2b);
        }
        float be2v = be2[e * 128 + wv * 32 + l31];
        #pragma unroll
        for (int r = 0; r < 16; ++r) {
            float eo = am2[r] + (a2a[r] + a2b[r]) * LO_INV + be2v;
            float gv = __shfl(gr[r], (lane & 32) + e, 64);
            out[r] += gv * eo;
        }
    }

    // ---- store (nontemporal; REC does read-modify-write) ----
    int col = wv * 32 + l31;
    #pragma unroll
    for (int r = 0; r < 16; ++r) {
        int row = (r & 3) + 8 * (r >> 2) + 4 * kg;
        size_t off = (size_t)(n0 + row) * 128 + col;
        float v = out[r];
        if (REC) {
            float sv = sbuf[(n0 + row) >> 2];
            float old = __builtin_nontemporal_load(&result[off]);
            v = old + v * sv;
        }
        __builtin_nontemporal_store(v, &result[off]);
    }
}

// ---------------- co / gate kernel (fp32 VALU, tiny) ----------------
__global__ __launch_bounds__(256) void co_kernel(
    const float* __restrict__ result, const float* __restrict__ Wog,
    const float* __restrict__ bog, float* __restrict__ sbuf, float thresh)
{
    int lane = threadIdx.x & 63;
    int w = threadIdx.x >> 6;
    int b = blockIdx.x * 4 + w;
    const float* r = result + (size_t)b * 512;
    float l0 = 0.f, l1 = 0.f;
    #pragma unroll
    for (int j = 0; j < 8; ++j) {
        int d = j * 64 + lane;
        float rv = __builtin_nontemporal_load(&r[d]);
        float2 wv = *(const float2*)&Wog[d * 2];
        l0 = fmaf(rv, wv.x, l0);
        l1 = fmaf(rv, wv.y, l1);
    }
    #pragma unroll
    for (int off = 32; off > 0; off >>= 1) {
        l0 += __shfl_down(l0, off);
        l1 += __shfl_down(l1, off);
    }
    if (lane == 0) {
        l0 += bog[0]; l1 += bog[1];
        float co0 = 1.f / (1.f + __expf(l1 - l0));
        sbuf[b] = (co0 > thresh) ? co0 : 0.f;
    }
}

// ---------------- Q head kernel (MFMA) ----------------
// 32 samples/block, 512 threads. values = relu(result@Wq1+bq1)@Wq2+bq2
__global__ __launch_bounds__(512, 2) void q_mfma(
    const float* __restrict__ result,
    const f16* __restrict__ Wq1H, const f16* __restrict__ Wq1L,
    const f16* __restrict__ Wq2H, const f16* __restrict__ Wq2L,
    const float* __restrict__ bq1, const float* __restrict__ bq2,
    float* __restrict__ out)
{
    extern __shared__ char smem[];
    f16* rh = (f16*)smem;              // [32][QS]
    f16* rl = rh + 32 * QS;
    f16* hh = rl + 32 * QS;
    f16* hl = hh + 32 * QS;
    float* part = (float*)(hl + 32 * QS);  // [4][1024]
    const int tid = threadIdx.x;
    const int lane = tid & 63;
    const int wv = tid >> 6;
    const int l31 = lane & 31;
    const int kg = lane >> 5;
    const int n0 = blockIdx.x * 32;

    // stage result rows (32x512) hi/lo
    #pragma unroll
    for (int i = 0; i < 8; ++i) {
        int idx = i * 512 + tid;
        int m = idx >> 7, k4 = (idx & 127) * 4;
        v4f v = nt_load4(&result[(size_t)(n0 + m) * 512 + k4]);
        f16x4 hv, lv;
        #pragma unroll
        for (int j = 0; j < 4; ++j) {
            hv[j] = (f16)v[j];
            lv[j] = (f16)((v[j] - (float)hv[j]) * LO_SCALE);
        }
        *(f16x4*)&rh[m * QS + k4] = hv;
        *(f16x4*)&rl[m * QS + k4] = lv;
    }
    __syncthreads();

    // GEMM1: hid(32x512) = relu(r @ Wq1 + bq1); 16 Ntiles / 8 waves
    f32x16 am0 = {}, ac0 = {}, am1 = {}, ac1 = {};
    const int nt0 = wv * 2;
    #pragma unroll
    for (int kt = 0; kt < 32; ++kt) {
        f16x8 ah = *(const f16x8*)&rh[l31 * QS + kt * 16 + kg * 8];
        f16x8 al = *(const f16x8*)&rl[l31 * QS + kt * 16 + kg * 8];
        f16x8 b0h = *(const f16x8*)(Wq1H + (size_t)(kt * 16 + nt0) * 512 + lane * 8);
        f16x8 b0l = *(const f16x8*)(Wq1L + (size_t)(kt * 16 + nt0) * 512 + lane * 8);
        f16x8 b1h = *(const f16x8*)(Wq1H + (size_t)(kt * 16 + nt0 + 1) * 512 + lane * 8);
        f16x8 b1l = *(const f16x8*)(Wq1L + (size_t)(kt * 16 + nt0 + 1) * 512 + lane * 8);
        am0 = MFMA(ah, b0h, am0); ac0 = MFMA(al, b0h, ac0); ac0 = MFMA(ah, b0l, ac0);
        am1 = MFMA(ah, b1h, am1); ac1 = MFMA(al, b1h, ac1); ac1 = MFMA(ah, b1l, ac1);
    }
    #pragma unroll
    for (int t = 0; t < 2; ++t) {
        int col = (nt0 + t) * 32 + l31;
        float b1v = bq1[col];
        #pragma unroll
        for (int r = 0; r < 16; ++r) {
            int row = (r & 3) + 8 * (r >> 2) + 4 * kg;
            float v = (t ? am1[r] + ac1[r] * LO_INV : am0[r] + ac0[r] * LO_INV) + b1v;
            v = fmaxf(v, 0.f);
            f16 hv = (f16)v;
            hh[row * QS + col] = hv;
            hl[row * QS + col] = (f16)((v - (float)hv) * LO_SCALE);
        }
    }
    __syncthreads();

    // GEMM2: values(32x18) = hid @ Wq2 + bq2; K split over waves 0-3
    if (wv < 4) {
        f32x16 am = {}, ac = {};
        #pragma unroll
        for (int k2 = 0; k2 < 8; ++k2) {
            int kt = wv * 8 + k2;
            f16x8 ah = *(const f16x8*)&hh[l31 * QS + kt * 16 + kg * 8];
            f16x8 al = *(const f16x8*)&hl[l31 * QS + kt * 16 + kg * 8];
            f16x8 bh = *(const f16x8*)(Wq2H + (size_t)kt * 512 + lane * 8);
            f16x8 bl = *(const f16x8*)(Wq2L + (size_t)kt * 512 + lane * 8);
            am = MFMA(ah, bh, am); ac = MFMA(al, bh, ac); ac = MFMA(ah, bl, ac);
        }
        #pragma unroll
        for (int r = 0; r < 16; ++r) {
            int row = (r & 3) + 8 * (r >> 2) + 4 * kg;
            part[wv * 1024 + row * 32 + l31] = am[r] + ac[r] * LO_INV;
        }
    }
    __syncthreads();
    for (int idx = tid; idx < 1024; idx += 512) {
        int row = idx >> 5, c = idx & 31;
        if (c < 18) {
            float s = part[idx] + part[1024 + idx] + part[2048 + idx] + part[3072 + idx]
                      + bq2[c];
            out[(size_t)(n0 + row) * 18 + c] = s;
        }
    }
}

extern "C" void kernel_launch(void* const* d_in, const int* in_sizes, int n_in,
                              void* d_out, int out_size, void* d_ws, size_t ws_size,
                              hipStream_t stream)
{
    (void)in_sizes; (void)n_in; (void)out_size; (void)ws_size;
    const float* data = (const float*)d_in[0];
    const float* We1  = (const float*)d_in[1];
    const float* be1  = (const float*)d_in[2];
    const float* We2  = (const float*)d_in[3];
    const float* be2  = (const float*)d_in[4];
    const float* Wg   = (const float*)d_in[5];
    const float* bg   = (const float*)d_in[6];
    const float* Wog  = (const float*)d_in[7];
    const float* bog  = (const float*)d_in[8];
    const float* Wr   = (const float*)d_in[9];
    const float* br   = (const float*)d_in[10];
    const float* Wq1  = (const float*)d_in[11];
    const float* bq1  = (const float*)d_in[12];
    const float* Wq2  = (const float*)d_in[13];
    const float* bq2  = (const float*)d_in[14];
    float* outp = (float*)d_out;

    float* result = (float*)d_ws;                         // 32768*128 fp32
    float* sbuf   = result + (size_t)32768 * 128;         // 8192 fp32
    f16* fb = (f16*)((char*)d_ws + 16809984);             // frag arrays base
    f16* W1H  = fb;
    f16* W1L  = fb + 524288;
    f16* W2H  = fb + 1048576;
    f16* W2L  = fb + 1310720;
    f16* WrH  = fb + 1572864;
    f16* WrL  = fb + 1605632;
    f16* WgH  = fb + 1638400;
    f16* WgL  = fb + 1646592;
    f16* Wq1H = fb + 1654784;
    f16* Wq1L = fb + 1916928;
    f16* Wq2H = fb + 2179072;
    f16* Wq2L = fb + 2195456;

    const int MOE_LDS = 4 * 32 * XS * 2;                  // 67584 B
    const int Q_LDS   = 4 * 32 * QS * 2 + 4 * 1024 * 4;   // 149504 B

    prep_kernel<<<540, 256, 0, stream>>>(We1, We2, Wr, Wg, Wq1, Wq2,
        W1H, W1L, W2H, W2L, WrH, WrL, WgH, WgL, Wq1H, Wq1L, Wq2H, Wq2L);

    moe_mfma<false><<<1024, 256, MOE_LDS, stream>>>(
        data, nullptr, W1H, W1L, W2H, W2L, WrH, WrL, WgH, WgL,
        be1, be2, bg, br, result);
    co_kernel<<<2048, 256, 0, stream>>>(result, Wog, bog, sbuf, 0.3f);
    moe_mfma<true><<<1024, 256, MOE_LDS, stream>>>(
        result, sbuf, W1H, W1L, W2H, W2L, WrH, WrL, WgH, WgL,
        be1, be2, bg, br, result);
    co_kernel<<<2048, 256, 0, stream>>>(result, Wog, bog, sbuf, 0.5f);
    moe_mfma<true><<<1024, 256, MOE_LDS, stream>>>(
        result, sbuf, W1H, W1L, W2H, W2L, WrH, WrL, WgH, WgL,
        be1, be2, bg, br, result);
    q_mfma<<<256, 512, Q_LDS, stream>>>(result, Wq1H, Wq1L, Wq2H, Wq2L,
        bq1, bq2, outp);
}

// Round 6
// 730.568 us; speedup vs baseline: 4.4700x; 1.0123x over previous
//
#include <hip/hip_runtime.h>
#include <math.h>

// B=8192, C=4, D=256, E=8, H=256, O=128, AQ=18, HQ=512, N=B*C=32768
//
// fp16-split (Ozaki) MFMA: v = hi + lo*2^-12, 3 MFMAs per product pair,
// fp32 accumulation -> ~2^-22 relative error, safe for co0>THRESH gates.
// R5 change vs R4 (latency diagnosis: no pipe >35% busy, VGPR=96 shows
// compiler kept a shallow B-load window):
//  - manual depth-2 software pipeline of all global B-fragment loads in
//    the four K-loops (explicit double buffers -> 8-16 L2 loads in
//    flight per wave, AITER-style vmcnt>0 overlap).

typedef _Float16 f16;
typedef f16   f16x8  __attribute__((ext_vector_type(8)));
typedef f16   f16x4  __attribute__((ext_vector_type(4)));
typedef float f32x16 __attribute__((ext_vector_type(16)));
typedef float v4f    __attribute__((ext_vector_type(4)));

#define MFMA(a, b, c) __builtin_amdgcn_mfma_f32_32x32x16_f16(a, b, c, 0, 0, 0)
#define LO_SCALE 4096.0f
#define LO_INV   (1.0f / 4096.0f)

#define XS 264   // f16 stride of 256-wide LDS rows (528B, 16B-aligned)
#define RS 136   // f16 stride of 128-wide LDS rows
#define QS 520   // f16 stride of 512-wide LDS rows (q kernel)

__device__ __forceinline__ v4f nt_load4(const float* p) {
    return __builtin_nontemporal_load((const v4f*)p);
}
__device__ __forceinline__ f16x8 ldg8(const f16* p) {
    return *(const f16x8*)p;
}

// ---------------- weight prep: fp32 -> frag-major fp16 hi/lo ----------------
// One 64-lane wave per 32n x 16k fragment tile. B[k][n]: n = lane&31,
// k = (lane>>5)*8 + j. Store: tile*512 + lane*8 + j.
__global__ __launch_bounds__(256) void prep_kernel(
    const float* __restrict__ We1, const float* __restrict__ We2,
    const float* __restrict__ Wr,  const float* __restrict__ Wg,
    const float* __restrict__ Wq1, const float* __restrict__ Wq2,
    f16* __restrict__ W1H, f16* __restrict__ W1L,
    f16* __restrict__ W2H, f16* __restrict__ W2L,
    f16* __restrict__ WrH, f16* __restrict__ WrL,
    f16* __restrict__ WgH, f16* __restrict__ WgL,
    f16* __restrict__ Wq1H, f16* __restrict__ Wq1L,
    f16* __restrict__ Wq2H, f16* __restrict__ Wq2L)
{
    int t = blockIdx.x * 4 + (threadIdx.x >> 6);
    int lane = threadIdx.x & 63;
    const float* src; f16 *dh, *dl;
    int stride, ncols, kbase, nbase, tile;
    if (t < 1024) {        // We1: (E,256,256) -> 8e x 16kt x 8nt
        int e = t >> 7, kt = (t >> 3) & 15, nt = t & 7;
        src = We1 + e * 65536; stride = 256; ncols = 256;
        kbase = kt * 16; nbase = nt * 32; tile = t; dh = W1H; dl = W1L;
    } else if (t < 1536) { // We2: (E,256,128) -> 8e x 16kt x 4nt
        int i = t - 1024; int e = i >> 6, kt = (i >> 2) & 15, nt = i & 3;
        src = We2 + e * 32768; stride = 128; ncols = 128;
        kbase = kt * 16; nbase = nt * 32; tile = i; dh = W2H; dl = W2L;
    } else if (t < 1600) { // Wr: (128,256) -> 8kt x 8nt
        int i = t - 1536; int kt = i >> 3, nt = i & 7;
        src = Wr; stride = 256; ncols = 256;
        kbase = kt * 16; nbase = nt * 32; tile = i; dh = WrH; dl = WrL;
    } else if (t < 1616) { // Wg: (256,8) pad n->32 -> 16kt x 1nt
        int i = t - 1600;
        src = Wg; stride = 8; ncols = 8;
        kbase = i * 16; nbase = 0; tile = i; dh = WgH; dl = WgL;
    } else if (t < 2128) { // Wq1: (512,512) -> 32kt x 16nt
        int i = t - 1616; int kt = i >> 4, nt = i & 15;
        src = Wq1; stride = 512; ncols = 512;
        kbase = kt * 16; nbase = nt * 32; tile = i; dh = Wq1H; dl = Wq1L;
    } else {               // Wq2: (512,18) pad n->32 -> 32kt x 1nt
        int i = t - 2128;
        src = Wq2; stride = 18; ncols = 18;
        kbase = i * 16; nbase = 0; tile = i; dh = Wq2H; dl = Wq2L;
    }
    int n = lane & 31, kg = lane >> 5;
    int col = nbase + n;
    f16x8 hv, lv;
    #pragma unroll
    for (int j = 0; j < 8; ++j) {
        int k = kbase + kg * 8 + j;
        float w = (col < ncols) ? src[(size_t)k * stride + col] : 0.f;
        f16 h = (f16)w;
        hv[j] = h;
        lv[j] = (f16)((w - (float)h) * LO_SCALE);
    }
    *(f16x8*)(dh + (size_t)tile * 512 + lane * 8) = hv;
    *(f16x8*)(dl + (size_t)tile * 512 + lane * 8) = lv;
}

// ---------------- fused MoE kernel (MFMA) ----------------
// 32 tokens/block, 256 threads = 4 waves, 1024 blocks, 2 blocks/CU.
// GEMM1/rec: wave w -> N-tiles {2w, 2w+1}, single M-tile (32 tokens).
// GEMM2: wave w -> N-tile w. Gating: all waves redundant, g via shfl.
// All B-fragment K-loops are depth-2 software-pipelined.
template<bool REC>
__global__ __launch_bounds__(256, 2) void moe_mfma(
    const float* xsrc, const float* __restrict__ sbuf,
    const f16* __restrict__ W1H, const f16* __restrict__ W1L,
    const f16* __restrict__ W2H, const f16* __restrict__ W2L,
    const f16* __restrict__ WrH, const f16* __restrict__ WrL,
    const f16* __restrict__ WgH, const f16* __restrict__ WgL,
    const float* __restrict__ be1, const float* __restrict__ be2,
    const float* __restrict__ bg,  const float* __restrict__ br,
    float* result)
{
    extern __shared__ char smem[];
    f16* xh = (f16*)smem;              // [32][XS]
    f16* xl = xh + 32 * XS;
    f16* hh = xl + 32 * XS;            // [32][XS]; rec stages r at stride RS
    f16* hl = hh + 32 * XS;

    const int tid = threadIdx.x;
    const int lane = tid & 63;
    const int wv = tid >> 6;           // 0..3
    const int l31 = lane & 31;
    const int kg = lane >> 5;
    const int n0 = blockIdx.x * 32;

    if (!REC) {
        // stage x (32x256 fp32) -> split hi/lo rows
        #pragma unroll
        for (int i = 0; i < 8; ++i) {
            int idx = i * 256 + tid;
            int m = idx >> 6, k4 = (idx & 63) * 4;
            v4f v = nt_load4(&xsrc[(size_t)(n0 + m) * 256 + k4]);
            f16x4 hv, lv;
            #pragma unroll
            for (int j = 0; j < 4; ++j) {
                hv[j] = (f16)v[j];
                lv[j] = (f16)((v[j] - (float)hv[j]) * LO_SCALE);
            }
            *(f16x4*)&xh[m * XS + k4] = hv;
            *(f16x4*)&xl[m * XS + k4] = lv;
        }
    } else {
        // stage r = result rows (32x128) into hh/hl at stride RS
        #pragma unroll
        for (int i = 0; i < 4; ++i) {
            int idx = i * 256 + tid;
            int m = idx >> 5, k4 = (idx & 31) * 4;
            v4f v = nt_load4(&xsrc[(size_t)(n0 + m) * 128 + k4]);
            f16x4 hv, lv;
            #pragma unroll
            for (int j = 0; j < 4; ++j) {
                hv[j] = (f16)v[j];
                lv[j] = (f16)((v[j] - (float)hv[j]) * LO_SCALE);
            }
            *(f16x4*)&hh[m * RS + k4] = hv;
            *(f16x4*)&hl[m * RS + k4] = lv;
        }
        __syncthreads();
        // rec GEMM: x(32x256) = r(32x128) @ Wr + br; wave w -> nt {2w,2w+1}
        f32x16 am0 = {}, a0a = {}, a0b = {}, am1 = {}, a1a = {}, a1b = {};
        const f16* wrh = WrH + (size_t)(2 * wv) * 512 + lane * 8;
        const f16* wrl = WrL + (size_t)(2 * wv) * 512 + lane * 8;
        f16x8 p0h = ldg8(wrh),       p0l = ldg8(wrl);
        f16x8 p1h = ldg8(wrh + 512), p1l = ldg8(wrl + 512);
        #pragma unroll
        for (int kt = 0; kt < 8; kt += 2) {
            f16x8 q0h = ldg8(wrh + (size_t)(kt + 1) * 4096);
            f16x8 q0l = ldg8(wrl + (size_t)(kt + 1) * 4096);
            f16x8 q1h = ldg8(wrh + (size_t)(kt + 1) * 4096 + 512);
            f16x8 q1l = ldg8(wrl + (size_t)(kt + 1) * 4096 + 512);
            f16x8 ah = *(const f16x8*)&hh[l31 * RS + kt * 16 + kg * 8];
            f16x8 al = *(const f16x8*)&hl[l31 * RS + kt * 16 + kg * 8];
            am0 = MFMA(ah, p0h, am0); a0a = MFMA(al, p0h, a0a); a0b = MFMA(ah, p0l, a0b);
            am1 = MFMA(ah, p1h, am1); a1a = MFMA(al, p1h, a1a); a1b = MFMA(ah, p1l, a1b);
            int ktn = (kt + 2) & 7;
            p0h = ldg8(wrh + (size_t)ktn * 4096);
            p0l = ldg8(wrl + (size_t)ktn * 4096);
            p1h = ldg8(wrh + (size_t)ktn * 4096 + 512);
            p1l = ldg8(wrl + (size_t)ktn * 4096 + 512);
            ah = *(const f16x8*)&hh[l31 * RS + (kt + 1) * 16 + kg * 8];
            al = *(const f16x8*)&hl[l31 * RS + (kt + 1) * 16 + kg * 8];
            am0 = MFMA(ah, q0h, am0); a0a = MFMA(al, q0h, a0a); a0b = MFMA(ah, q0l, a0b);
            am1 = MFMA(ah, q1h, am1); a1a = MFMA(al, q1h, a1a); a1b = MFMA(ah, q1l, a1b);
        }
        #pragma unroll
        for (int t = 0; t < 2; ++t) {
            int col = (2 * wv + t) * 32 + l31;
            float brv = br[col];
            #pragma unroll
            for (int r = 0; r < 16; ++r) {
                int row = (r & 3) + 8 * (r >> 2) + 4 * kg;
                float v = (t ? am1[r] + (a1a[r] + a1b[r]) * LO_INV
                             : am0[r] + (a0a[r] + a0b[r]) * LO_INV) + brv;
                f16 hv = (f16)v;
                xh[row * XS + col] = hv;
                xl[row * XS + col] = (f16)((v - (float)hv) * LO_SCALE);
            }
        }
    }
    __syncthreads();

    // ---- gating (all waves redundant): logits = x @ Wg + bg ----
    float gr[16];
    {
        f32x16 gm = {}, ga = {}, gb = {};
        const f16* wgh = WgH + lane * 8;
        const f16* wgl = WgL + lane * 8;
        f16x8 ph = ldg8(wgh), pl = ldg8(wgl);
        #pragma unroll
        for (int kt = 0; kt < 16; kt += 2) {
            f16x8 qh = ldg8(wgh + (size_t)(kt + 1) * 512);
            f16x8 ql = ldg8(wgl + (size_t)(kt + 1) * 512);
            f16x8 ah = *(const f16x8*)&xh[l31 * XS + kt * 16 + kg * 8];
            f16x8 al = *(const f16x8*)&xl[l31 * XS + kt * 16 + kg * 8];
            gm = MFMA(ah, ph, gm); ga = MFMA(al, ph, ga); gb = MFMA(ah, pl, gb);
            int ktn = (kt + 2) & 15;
            ph = ldg8(wgh + (size_t)ktn * 512);
            pl = ldg8(wgl + (size_t)ktn * 512);
            ah = *(const f16x8*)&xh[l31 * XS + (kt + 1) * 16 + kg * 8];
            al = *(const f16x8*)&xl[l31 * XS + (kt + 1) * 16 + kg * 8];
            gm = MFMA(ah, qh, gm); ga = MFMA(al, qh, ga); gb = MFMA(ah, ql, gb);
        }
        float bge = (l31 < 8) ? bg[l31] : 0.f;
        #pragma unroll
        for (int r = 0; r < 16; ++r) {
            float lg = gm[r] + (ga[r] + gb[r]) * LO_INV + bge;
            float mx = lg;
            #pragma unroll
            for (int d = 1; d < 8; d <<= 1) mx = fmaxf(mx, __shfl_xor(mx, d, 64));
            float ex = __expf(lg - mx);
            float s = ex;
            #pragma unroll
            for (int d = 1; d < 8; d <<= 1) s += __shfl_xor(s, d, 64);
            gr[r] = ex / s;   // valid on lanes l31<8 (e=l31); others unused
        }
    }

    // ---- expert loop ----
    f32x16 out = {};
    #pragma unroll 1
    for (int e = 0; e < 8; ++e) {
        // GEMM1: h(32x256) = relu(x @ We1[e] + be1[e]); wave w -> nt {2w,2w+1}
        f32x16 am0 = {}, a0a = {}, a0b = {}, am1 = {}, a1a = {}, a1b = {};
        const f16* w1h = W1H + (size_t)e * 65536 + (2 * wv) * 512 + lane * 8;
        const f16* w1l = W1L + (size_t)e * 65536 + (2 * wv) * 512 + lane * 8;
        {
            f16x8 p0h = ldg8(w1h),       p0l = ldg8(w1l);
            f16x8 p1h = ldg8(w1h + 512), p1l = ldg8(w1l + 512);
            #pragma unroll
            for (int kt = 0; kt < 16; kt += 2) {
                f16x8 q0h = ldg8(w1h + (size_t)(kt + 1) * 4096);
                f16x8 q0l = ldg8(w1l + (size_t)(kt + 1) * 4096);
                f16x8 q1h = ldg8(w1h + (size_t)(kt + 1) * 4096 + 512);
                f16x8 q1l = ldg8(w1l + (size_t)(kt + 1) * 4096 + 512);
                f16x8 ah = *(const f16x8*)&xh[l31 * XS + kt * 16 + kg * 8];
                f16x8 al = *(const f16x8*)&xl[l31 * XS + kt * 16 + kg * 8];
                am0 = MFMA(ah, p0h, am0); a0a = MFMA(al, p0h, a0a); a0b = MFMA(ah, p0l, a0b);
                am1 = MFMA(ah, p1h, am1); a1a = MFMA(al, p1h, a1a); a1b = MFMA(ah, p1l, a1b);
                int ktn = (kt + 2) & 15;
                p0h = ldg8(w1h + (size_t)ktn * 4096);
                p0l = ldg8(w1l + (size_t)ktn * 4096);
                p1h = ldg8(w1h + (size_t)ktn * 4096 + 512);
                p1l = ldg8(w1l + (size_t)ktn * 4096 + 512);
                ah = *(const f16x8*)&xh[l31 * XS + (kt + 1) * 16 + kg * 8];
                al = *(const f16x8*)&xl[l31 * XS + (kt + 1) * 16 + kg * 8];
                am0 = MFMA(ah, q0h, am0); a0a = MFMA(al, q0h, a0a); a0b = MFMA(ah, q0l, a0b);
                am1 = MFMA(ah, q1h, am1); a1a = MFMA(al, q1h, a1a); a1b = MFMA(ah, q1l, a1b);
            }
        }
        __syncthreads();   // previous GEMM2 readers of hh/hl are done
        #pragma unroll
        for (int t = 0; t < 2; ++t) {
            int col = (2 * wv + t) * 32 + l31;
            float b1v = be1[e * 256 + col];
            #pragma unroll
            for (int r = 0; r < 16; ++r) {
                int row = (r & 3) + 8 * (r >> 2) + 4 * kg;
                float v = (t ? am1[r] + (a1a[r] + a1b[r]) * LO_INV
                             : am0[r] + (a0a[r] + a0b[r]) * LO_INV) + b1v;
                v = fmaxf(v, 0.f);
                f16 hv = (f16)v;
                hh[row * XS + col] = hv;
                hl[row * XS + col] = (f16)((v - (float)hv) * LO_SCALE);
            }
        }
        __syncthreads();
        // GEMM2: eo(32x128) = h @ We2[e]; out += g_e*(eo + be2)
        f32x16 am2 = {}, a2a = {}, a2b = {};
        const f16* w2h = W2H + (size_t)e * 32768 + wv * 512 + lane * 8;
        const f16* w2l = W2L + (size_t)e * 32768 + wv * 512 + lane * 8;
        {
            f16x8 ph = ldg8(w2h), pl = ldg8(w2l);
            #pragma unroll
            for (int kt = 0; kt < 16; kt += 2) {
                f16x8 qh = ldg8(w2h + (size_t)(kt + 1) * 2048);
                f16x8 ql = ldg8(w2l + (size_t)(kt + 1) * 2048);
                f16x8 ah = *(const f16x8*)&hh[l31 * XS + kt * 16 + kg * 8];
                f16x8 al = *(const f16x8*)&hl[l31 * XS + kt * 16 + kg * 8];
                am2 = MFMA(ah, ph, am2); a2a = MFMA(al, ph, a2a); a2b = MFMA(ah, pl, a2b);
                int ktn = (kt + 2) & 15;
                ph = ldg8(w2h + (size_t)ktn * 2048);
                pl = ldg8(w2l + (size_t)ktn * 2048);
                ah = *(const f16x8*)&hh[l31 * XS + (kt + 1) * 16 + kg * 8];
                al = *(const f16x8*)&hl[l31 * XS + (kt + 1) * 16 + kg * 8];
                am2 = MFMA(ah, qh, am2); a2a = MFMA(al, qh, a2a); a2b = MFMA(ah, ql, a2b);
            }
        }
        float be2v = be2[e * 128 + wv * 32 + l31];
        #pragma unroll
        for (int r = 0; r < 16; ++r) {
            float eo = am2[r] + (a2a[r] + a2b[r]) * LO_INV + be2v;
            float gv = __shfl(gr[r], (lane & 32) + e, 64);
            out[r] += gv * eo;
        }
    }

    // ---- store (nontemporal; REC does read-modify-write) ----
    int col = wv * 32 + l31;
    #pragma unroll
    for (int r = 0; r < 16; ++r) {
        int row = (r & 3) + 8 * (r >> 2) + 4 * kg;
        size_t off = (size_t)(n0 + row) * 128 + col;
        float v = out[r];
        if (REC) {
            float sv = sbuf[(n0 + row) >> 2];
            float old = __builtin_nontemporal_load(&result[off]);
            v = old + v * sv;
        }
        __builtin_nontemporal_store(v, &result[off]);
    }
}

// ---------------- co / gate kernel (fp32 VALU, tiny) ----------------
__global__ __launch_bounds__(256) void co_kernel(
    const float* __restrict__ result, const float* __restrict__ Wog,
    const float* __restrict__ bog, float* __restrict__ sbuf, float thresh)
{
    int lane = threadIdx.x & 63;
    int w = threadIdx.x >> 6;
    int b = blockIdx.x * 4 + w;
    const float* r = result + (size_t)b * 512;
    float l0 = 0.f, l1 = 0.f;
    #pragma unroll
    for (int j = 0; j < 8; ++j) {
        int d = j * 64 + lane;
        float rv = __builtin_nontemporal_load(&r[d]);
        float2 wv = *(const float2*)&Wog[d * 2];
        l0 = fmaf(rv, wv.x, l0);
        l1 = fmaf(rv, wv.y, l1);
    }
    #pragma unroll
    for (int off = 32; off > 0; off >>= 1) {
        l0 += __shfl_down(l0, off);
        l1 += __shfl_down(l1, off);
    }
    if (lane == 0) {
        l0 += bog[0]; l1 += bog[1];
        float co0 = 1.f / (1.f + __expf(l1 - l0));
        sbuf[b] = (co0 > thresh) ? co0 : 0.f;
    }
}

// ---------------- Q head kernel (MFMA) ----------------
// 32 samples/block, 512 threads. values = relu(result@Wq1+bq1)@Wq2+bq2
__global__ __launch_bounds__(512, 2) void q_mfma(
    const float* __restrict__ result,
    const f16* __restrict__ Wq1H, const f16* __restrict__ Wq1L,
    const f16* __restrict__ Wq2H, const f16* __restrict__ Wq2L,
    const float* __restrict__ bq1, const float* __restrict__ bq2,
    float* __restrict__ out)
{
    extern __shared__ char smem[];
    f16* rh = (f16*)smem;              // [32][QS]
    f16* rl = rh + 32 * QS;
    f16* hh = rl + 32 * QS;
    f16* hl = hh + 32 * QS;
    float* part = (float*)(hl + 32 * QS);  // [4][1024]
    const int tid = threadIdx.x;
    const int lane = tid & 63;
    const int wv = tid >> 6;
    const int l31 = lane & 31;
    const int kg = lane >> 5;
    const int n0 = blockIdx.x * 32;

    // stage result rows (32x512) hi/lo
    #pragma unroll
    for (int i = 0; i < 8; ++i) {
        int idx = i * 512 + tid;
        int m = idx >> 7, k4 = (idx & 127) * 4;
        v4f v = nt_load4(&result[(size_t)(n0 + m) * 512 + k4]);
        f16x4 hv, lv;
        #pragma unroll
        for (int j = 0; j < 4; ++j) {
            hv[j] = (f16)v[j];
            lv[j] = (f16)((v[j] - (float)hv[j]) * LO_SCALE);
        }
        *(f16x4*)&rh[m * QS + k4] = hv;
        *(f16x4*)&rl[m * QS + k4] = lv;
    }
    __syncthreads();

    // GEMM1: hid(32x512) = relu(r @ Wq1 + bq1); 16 Ntiles / 8 waves
    f32x16 am0 = {}, ac0 = {}, am1 = {}, ac1 = {};
    const int nt0 = wv * 2;
    #pragma unroll
    for (int kt = 0; kt < 32; ++kt) {
        f16x8 ah = *(const f16x8*)&rh[l31 * QS + kt * 16 + kg * 8];
        f16x8 al = *(const f16x8*)&rl[l31 * QS + kt * 16 + kg * 8];
        f16x8 b0h = *(const f16x8*)(Wq1H + (size_t)(kt * 16 + nt0) * 512 + lane * 8);
        f16x8 b0l = *(const f16x8*)(Wq1L + (size_t)(kt * 16 + nt0) * 512 + lane * 8);
        f16x8 b1h = *(const f16x8*)(Wq1H + (size_t)(kt * 16 + nt0 + 1) * 512 + lane * 8);
        f16x8 b1l = *(const f16x8*)(Wq1L + (size_t)(kt * 16 + nt0 + 1) * 512 + lane * 8);
        am0 = MFMA(ah, b0h, am0); ac0 = MFMA(al, b0h, ac0); ac0 = MFMA(ah, b0l, ac0);
        am1 = MFMA(ah, b1h, am1); ac1 = MFMA(al, b1h, ac1); ac1 = MFMA(ah, b1l, ac1);
    }
    #pragma unroll
    for (int t = 0; t < 2; ++t) {
        int col = (nt0 + t) * 32 + l31;
        float b1v = bq1[col];
        #pragma unroll
        for (int r = 0; r < 16; ++r) {
            int row = (r & 3) + 8 * (r >> 2) + 4 * kg;
            float v = (t ? am1[r] + ac1[r] * LO_INV : am0[r] + ac0[r] * LO_INV) + b1v;
            v = fmaxf(v, 0.f);
            f16 hv = (f16)v;
            hh[row * QS + col] = hv;
            hl[row * QS + col] = (f16)((v - (float)hv) * LO_SCALE);
        }
    }
    __syncthreads();

    // GEMM2: values(32x18) = hid @ Wq2 + bq2; K split over waves 0-3
    if (wv < 4) {
        f32x16 am = {}, ac = {};
        #pragma unroll
        for (int k2 = 0; k2 < 8; ++k2) {
            int kt = wv * 8 + k2;
            f16x8 ah = *(const f16x8*)&hh[l31 * QS + kt * 16 + kg * 8];
            f16x8 al = *(const f16x8*)&hl[l31 * QS + kt * 16 + kg * 8];
            f16x8 bh = *(const f16x8*)(Wq2H + (size_t)kt * 512 + lane * 8);
            f16x8 bl = *(const f16x8*)(Wq2L + (size_t)kt * 512 + lane * 8);
            am = MFMA(ah, bh, am); ac = MFMA(al, bh, ac); ac = MFMA(ah, bl, ac);
        }
        #pragma unroll
        for (int r = 0; r < 16; ++r) {
            int row = (r & 3) + 8 * (r >> 2) + 4 * kg;
            part[wv * 1024 + row * 32 + l31] = am[r] + ac[r] * LO_INV;
        }
    }
    __syncthreads();
    for (int idx = tid; idx < 1024; idx += 512) {
        int row = idx >> 5, c = idx & 31;
        if (c < 18) {
            float s = part[idx] + part[1024 + idx] + part[2048 + idx] + part[3072 + idx]
                      + bq2[c];
            out[(size_t)(n0 + row) * 18 + c] = s;
        }
    }
}

extern "C" void kernel_launch(void* const* d_in, const int* in_sizes, int n_in,
                              void* d_out, int out_size, void* d_ws, size_t ws_size,
                              hipStream_t stream)
{
    (void)in_sizes; (void)n_in; (void)out_size; (void)ws_size;
    const float* data = (const float*)d_in[0];
    const float* We1  = (const float*)d_in[1];
    const float* be1  = (const float*)d_in[2];
    const float* We2  = (const float*)d_in[3];
    const float* be2  = (const float*)d_in[4];
    const float* Wg   = (const float*)d_in[5];
    const float* bg   = (const float*)d_in[6];
    const float* Wog  = (const float*)d_in[7];
    const float* bog  = (const float*)d_in[8];
    const float* Wr   = (const float*)d_in[9];
    const float* br   = (const float*)d_in[10];
    const float* Wq1  = (const float*)d_in[11];
    const float* bq1  = (const float*)d_in[12];
    const float* Wq2  = (const float*)d_in[13];
    const float* bq2  = (const float*)d_in[14];
    float* outp = (float*)d_out;

    float* result = (float*)d_ws;                         // 32768*128 fp32
    float* sbuf   = result + (size_t)32768 * 128;         // 8192 fp32
    f16* fb = (f16*)((char*)d_ws + 16809984);             // frag arrays base
    f16* W1H  = fb;
    f16* W1L  = fb + 524288;
    f16* W2H  = fb + 1048576;
    f16* W2L  = fb + 1310720;
    f16* WrH  = fb + 1572864;
    f16* WrL  = fb + 1605632;
    f16* WgH  = fb + 1638400;
    f16* WgL  = fb + 1646592;
    f16* Wq1H = fb + 1654784;
    f16* Wq1L = fb + 1916928;
    f16* Wq2H = fb + 2179072;
    f16* Wq2L = fb + 2195456;

    const int MOE_LDS = 4 * 32 * XS * 2;                  // 67584 B
    const int Q_LDS   = 4 * 32 * QS * 2 + 4 * 1024 * 4;   // 149504 B

    prep_kernel<<<540, 256, 0, stream>>>(We1, We2, Wr, Wg, Wq1, Wq2,
        W1H, W1L, W2H, W2L, WrH, WrL, WgH, WgL, Wq1H, Wq1L, Wq2H, Wq2L);

    moe_mfma<false><<<1024, 256, MOE_LDS, stream>>>(
        data, nullptr, W1H, W1L, W2H, W2L, WrH, WrL, WgH, WgL,
        be1, be2, bg, br, result);
    co_kernel<<<2048, 256, 0, stream>>>(result, Wog, bog, sbuf, 0.3f);
    moe_mfma<true><<<1024, 256, MOE_LDS, stream>>>(
        result, sbuf, W1H, W1L, W2H, W2L, WrH, WrL, WgH, WgL,
        be1, be2, bg, br, result);
    co_kernel<<<2048, 256, 0, stream>>>(result, Wog, bog, sbuf, 0.5f);
    moe_mfma<true><<<1024, 256, MOE_LDS, stream>>>(
        result, sbuf, W1H, W1L, W2H, W2L, WrH, WrL, WgH, WgL,
        be1, be2, bg, br, result);
    q_mfma<<<256, 512, Q_LDS, stream>>>(result, Wq1H, Wq1L, Wq2H, Wq2L,
        bq1, bq2, outp);
}